// Round 8
// baseline (513.633 us; speedup 1.0000x reference)
//
#include <hip/hip_runtime.h>
#include <hip/hip_bf16.h>
#include <math.h>

#define NNODES 100000
#define NEDGES 3200000
#define NBUK ((NNODES + 127) >> 7)   // 782 buckets of 128 nodes
#define NCHUNK 128
#define EPC (NEDGES / NCHUNK)        // 25000 edges per chunk

typedef float floatx2 __attribute__((ext_vector_type(2)));

// ---- bf16 pack/unpack ----
__device__ __forceinline__ unsigned short f2bf(float x) {
    unsigned u = __float_as_uint(x);
    unsigned r = u + 0x7FFFu + ((u >> 16) & 1u);
    return (unsigned short)(r >> 16);
}
__device__ __forceinline__ void unpack8_bf16(uint4 v, float* f) {
    f[0] = __uint_as_float(v.x << 16); f[1] = __uint_as_float(v.x & 0xFFFF0000u);
    f[2] = __uint_as_float(v.y << 16); f[3] = __uint_as_float(v.y & 0xFFFF0000u);
    f[4] = __uint_as_float(v.z << 16); f[5] = __uint_as_float(v.z & 0xFFFF0000u);
    f[6] = __uint_as_float(v.w << 16); f[7] = __uint_as_float(v.w & 0xFFFF0000u);
}

// ---- fp8 e4m3 packed accumulate (gfx950 HW converts; v_pk_add_f32 adds) ----
__device__ __forceinline__ void acc8_fp8(uint2 v, floatx2* a) {
    a[0] += __builtin_amdgcn_cvt_pk_f32_fp8(v.x, false);
    a[1] += __builtin_amdgcn_cvt_pk_f32_fp8(v.x, true);
    a[2] += __builtin_amdgcn_cvt_pk_f32_fp8(v.y, false);
    a[3] += __builtin_amdgcn_cvt_pk_f32_fp8(v.y, true);
}
__device__ __forceinline__ void acc4_fp8(unsigned v, floatx2* a) {
    a[0] += __builtin_amdgcn_cvt_pk_f32_fp8(v, false);
    a[1] += __builtin_amdgcn_cvt_pk_f32_fp8(v, true);
}

// ---------------- pass 1: per-chunk bucket histogram (LDS) ----------------
__global__ __launch_bounds__(1024) void chunk_hist_kernel(const int* __restrict__ dst,
                                                          int* __restrict__ hist) {
    __shared__ int h[NBUK];
    int c = blockIdx.x, t = threadIdx.x;
    for (int i = t; i < NBUK; i += 1024) h[i] = 0;
    __syncthreads();
    int e0 = c * EPC, e1 = e0 + EPC;
    for (int e = e0 + t; e < e1; e += 1024)
        atomicAdd(&h[dst[e] >> 7], 1);
    __syncthreads();
    for (int i = t; i < NBUK; i += 1024)
        hist[c * NBUK + i] = h[i];
}

// ---------------- pass 2: per-bucket exclusive prefix over chunks ----------------
__global__ void col_scan_kernel(int* __restrict__ hist, int* __restrict__ btot) {
    int t = blockIdx.x * 256 + threadIdx.x;
    if (t >= NBUK) return;
    int run = 0;
    for (int c = 0; c < NCHUNK; c++) {
        int idx = c * NBUK + t;
        int v = hist[idx];
        hist[idx] = run;
        run += v;
    }
    btot[t] = run;
}

// ---------------- pass 3: scan bucket totals -> bstart; zero small accumulators ----------------
__global__ void bucket_scan_kernel(const int* __restrict__ btot, int* __restrict__ bstart,
                                   int* __restrict__ row_start, float* __restrict__ smalls) {
    __shared__ int s[1024];
    int t = threadIdx.x;
    if (t < 592) smalls[t] = 0.0f;   // colsum(8) ata(64) ge(512)
    int v = (t < NBUK) ? btot[t] : 0;
    s[t] = v;
    __syncthreads();
    for (int off = 1; off < 1024; off <<= 1) {
        int x = (t >= off) ? s[t - off] : 0;
        __syncthreads();
        s[t] += x;
        __syncthreads();
    }
    if (t < NBUK) bstart[t] = s[t] - v;
    if (t == 0) {
        bstart[NBUK] = NEDGES;
        row_start[NNODES] = NEDGES;
    }
}

// ---------------- pass 4: deterministic scatter into bucket order (LDS cursors) ----------------
__global__ __launch_bounds__(1024) void chunk_scatter_kernel(const int* __restrict__ src,
                                                             const int* __restrict__ dst,
                                                             const int* __restrict__ hist,
                                                             const int* __restrict__ bstart,
                                                             int* __restrict__ ebuk) {
    __shared__ int cur[NBUK];
    int c = blockIdx.x, t = threadIdx.x;
    for (int i = t; i < NBUK; i += 1024)
        cur[i] = bstart[i] + hist[c * NBUK + i];
    __syncthreads();
    int e0 = c * EPC, e1 = e0 + EPC;
    for (int e = e0 + t; e < e1; e += 1024) {
        int d = dst[e];
        int pos = atomicAdd(&cur[d >> 7], 1);
        ebuk[pos] = src[e] | ((d & 127) << 20);   // src < 2^17 fits in 20 bits
    }
}

// ---------------- per-bucket: node counts, row_start, dinv, csr fill ----------------
__global__ __launch_bounds__(256) void build_kernel(const int* __restrict__ ebuk,
                                                    const int* __restrict__ bstart,
                                                    int* __restrict__ row_start,
                                                    float* __restrict__ dinv,
                                                    int* __restrict__ csr) {
    __shared__ int cnt[128];
    __shared__ int cur[128];
    int b = blockIdx.x;
    int t = threadIdx.x;
    int s0 = bstart[b], s1 = bstart[b + 1];
    if (t < 128) cnt[t] = 0;
    __syncthreads();
    for (int i = s0 + t; i < s1; i += 256)
        atomicAdd(&cnt[(ebuk[i] >> 20) & 127], 1);
    __syncthreads();
    if (t == 0) {
        int run = s0;
        for (int i = 0; i < 128; i++) { cur[i] = run; run += cnt[i]; }
    }
    __syncthreads();
    int node = b * 128 + t;
    if (t < 128 && node < NNODES) {
        row_start[node] = cur[t];
        dinv[node] = rsqrtf((float)cnt[t] + 1.0f);
    }
    __syncthreads();
    for (int i = s0 + t; i < s1; i += 256) {
        int v = ebuk[i];
        int pos = atomicAdd(&cur[(v >> 20) & 127], 1);
        csr[pos] = v & 0xFFFFF;
    }
}

// ---------------- register-tiled GEMM (fp32 A): stage(fp8) = rowscale * (A @ W) ----------------
template <int KIN, int KOUT, int TR>
__global__ __launch_bounds__(256) void gemm_stage_kernel(const float* __restrict__ A,
                                                         const float* __restrict__ W,
                                                         const float* __restrict__ rowscale,
                                                         unsigned char* __restrict__ stage,
                                                         int nrows) {
    constexpr int COLG = KOUT / 4;
    constexpr int ROWG = 256 / COLG;
    constexpr int R    = TR / ROWG;
    constexpr int LDK  = KIN + 4;
    __shared__ float As[TR][LDK];
    int block_row = blockIdx.x * TR;
    int tid = threadIdx.x;

    constexpr int C4 = KIN / 4;
    for (int idx = tid; idx < TR * C4; idx += 256) {
        int r = idx / C4, c = idx % C4;
        float4 v = make_float4(0.f, 0.f, 0.f, 0.f);
        if (block_row + r < nrows)
            v = *(const float4*)(A + (size_t)(block_row + r) * KIN + c * 4);
        *(float4*)(&As[r][c * 4]) = v;
    }
    __syncthreads();

    int cg = tid % COLG, rg = tid / COLG;
    int j  = cg * 4;
    int r0 = rg * R;
    float4 acc[R];
#pragma unroll
    for (int r = 0; r < R; r++) acc[r] = make_float4(0.f, 0.f, 0.f, 0.f);

#pragma unroll 4
    for (int k = 0; k < KIN; k++) {
        float4 w = *(const float4*)(W + (size_t)k * KOUT + j);
#pragma unroll
        for (int r = 0; r < R; r++) {
            float a = As[r0 + r][k];
            acc[r].x += a * w.x; acc[r].y += a * w.y;
            acc[r].z += a * w.z; acc[r].w += a * w.w;
        }
    }
#pragma unroll
    for (int r = 0; r < R; r++) {
        int row = block_row + r0 + r;
        if (row < nrows) {
            float d = rowscale[row];
            int pk = __builtin_amdgcn_cvt_pk_fp8_f32(acc[r].x * d, acc[r].y * d, 0, false);
            pk = __builtin_amdgcn_cvt_pk_fp8_f32(acc[r].z * d, acc[r].w * d, pk, true);
            *(unsigned*)(stage + (size_t)row * KOUT + j) = (unsigned)pk;
        }
    }
}

// ---------------- register-tiled GEMM (bf16 A): stage(fp8) = rowscale * (A @ W) ----------------
template <int KIN, int KOUT, int TR>
__global__ __launch_bounds__(256) void gemm_stage_bf16_kernel(const unsigned short* __restrict__ A,
                                                              const float* __restrict__ W,
                                                              const float* __restrict__ rowscale,
                                                              unsigned char* __restrict__ stage,
                                                              int nrows) {
    constexpr int COLG = KOUT / 4;
    constexpr int ROWG = 256 / COLG;
    constexpr int R    = TR / ROWG;
    constexpr int LDK  = KIN + 4;
    __shared__ float As[TR][LDK];
    int block_row = blockIdx.x * TR;
    int tid = threadIdx.x;

    constexpr int C8 = KIN / 8;
    for (int idx = tid; idx < TR * C8; idx += 256) {
        int r = idx / C8, c = idx % C8;
        float f[8];
        uint4 v = make_uint4(0, 0, 0, 0);
        if (block_row + r < nrows)
            v = *(const uint4*)(A + (size_t)(block_row + r) * KIN + c * 8);
        unpack8_bf16(v, f);
#pragma unroll
        for (int i = 0; i < 8; i++) As[r][c * 8 + i] = f[i];
    }
    __syncthreads();

    int cg = tid % COLG, rg = tid / COLG;
    int j  = cg * 4;
    int r0 = rg * R;
    float4 acc[R];
#pragma unroll
    for (int r = 0; r < R; r++) acc[r] = make_float4(0.f, 0.f, 0.f, 0.f);

#pragma unroll 4
    for (int k = 0; k < KIN; k++) {
        float4 w = *(const float4*)(W + (size_t)k * KOUT + j);
#pragma unroll
        for (int r = 0; r < R; r++) {
            float a = As[r0 + r][k];
            acc[r].x += a * w.x; acc[r].y += a * w.y;
            acc[r].z += a * w.z; acc[r].w += a * w.w;
        }
    }
#pragma unroll
    for (int r = 0; r < R; r++) {
        int row = block_row + r0 + r;
        if (row < nrows) {
            float d = rowscale[row];
            int pk = __builtin_amdgcn_cvt_pk_fp8_f32(acc[r].x * d, acc[r].y * d, 0, false);
            pk = __builtin_amdgcn_cvt_pk_fp8_f32(acc[r].z * d, acc[r].w * d, pk, true);
            *(unsigned*)(stage + (size_t)row * KOUT + j) = (unsigned)pk;
        }
    }
}

// ---------------- gather K=128 fp8: one node/wave, 4 lane-groups x 16 lanes, uint2/lane ----------------
// out: bf16 h1 row (relu((agg+self)*dinv + b))
__global__ __launch_bounds__(256) void gather128_kernel(
    const unsigned char* __restrict__ hs, const int* __restrict__ row_start,
    const int* __restrict__ csr, const float* __restrict__ dinv,
    const float* __restrict__ bias, unsigned short* __restrict__ out) {
    int wave = threadIdx.x >> 6;
    int lane = threadIdx.x & 63;
    int n = blockIdx.x * 4 + wave;
    if (n >= NNODES) return;
    int g = lane >> 4;          // 0..3: edge sub-group
    int c = lane & 15;          // uint2 index within 128 B row
    unsigned cb = (unsigned)c << 3;   // byte offset within row
    int start = row_start[n], end = row_start[n + 1];
    floatx2 acc[4];
#pragma unroll
    for (int i = 0; i < 4; i++) acc[i] = (floatx2)(0.f);
    int e = start + g;
    for (; e + 4 < end; e += 8) {
        unsigned o0 = ((unsigned)csr[e] << 7) + cb;
        unsigned o1 = ((unsigned)csr[e + 4] << 7) + cb;
        uint2 v0 = *(const uint2*)(hs + o0);
        uint2 v1 = *(const uint2*)(hs + o1);
        acc8_fp8(v0, acc);
        acc8_fp8(v1, acc);
    }
    for (; e < end; e += 4) {
        unsigned o = ((unsigned)csr[e] << 7) + cb;
        acc8_fp8(*(const uint2*)(hs + o), acc);
    }
#pragma unroll
    for (int off = 16; off <= 32; off <<= 1)
#pragma unroll
        for (int i = 0; i < 4; i++) {
            acc[i].x += __shfl_xor(acc[i].x, off);
            acc[i].y += __shfl_xor(acc[i].y, off);
        }
    if (g == 0) {
        floatx2 s[4];
#pragma unroll
        for (int i = 0; i < 4; i++) s[i] = (floatx2)(0.f);
        acc8_fp8(*(const uint2*)(hs + (((unsigned)n << 7) + cb)), s);
        float d = dinv[n];
        int j = c * 8;
        float4 b0 = *(const float4*)(bias + j);
        float4 b1 = *(const float4*)(bias + j + 4);
        float r0 = fmaxf((acc[0].x + s[0].x) * d + b0.x, 0.f);
        float r1 = fmaxf((acc[0].y + s[0].y) * d + b0.y, 0.f);
        float r2 = fmaxf((acc[1].x + s[1].x) * d + b0.z, 0.f);
        float r3 = fmaxf((acc[1].y + s[1].y) * d + b0.w, 0.f);
        float r4 = fmaxf((acc[2].x + s[2].x) * d + b1.x, 0.f);
        float r5 = fmaxf((acc[2].y + s[2].y) * d + b1.y, 0.f);
        float r6 = fmaxf((acc[3].x + s[3].x) * d + b1.z, 0.f);
        float r7 = fmaxf((acc[3].y + s[3].y) * d + b1.w, 0.f);
        uint4 p;
        p.x = (unsigned)f2bf(r0) | ((unsigned)f2bf(r1) << 16);
        p.y = (unsigned)f2bf(r2) | ((unsigned)f2bf(r3) << 16);
        p.z = (unsigned)f2bf(r4) | ((unsigned)f2bf(r5) << 16);
        p.w = (unsigned)f2bf(r6) | ((unsigned)f2bf(r7) << 16);
        *(uint4*)(out + (((size_t)n << 7) + j)) = p;
    }
}

// ---------------- gather K=64 fp8: one node/wave, 4 lane-groups x 16 lanes, uint/lane ----------------
__global__ __launch_bounds__(256) void gather64_kernel(
    const unsigned char* __restrict__ hs, const int* __restrict__ row_start,
    const int* __restrict__ csr, const float* __restrict__ dinv,
    const float* __restrict__ bias, float* __restrict__ out) {
    int wave = threadIdx.x >> 6;
    int lane = threadIdx.x & 63;
    int n = blockIdx.x * 4 + wave;
    if (n >= NNODES) return;
    int g = lane >> 4;          // 0..3: edge sub-group
    int c = lane & 15;          // uint index within 64 B row
    unsigned cb = (unsigned)c << 2;
    int start = row_start[n], end = row_start[n + 1];
    floatx2 acc[2];
    acc[0] = (floatx2)(0.f); acc[1] = (floatx2)(0.f);
    int e = start + g;
    for (; e + 4 < end; e += 8) {
        unsigned o0 = ((unsigned)csr[e] << 6) + cb;
        unsigned o1 = ((unsigned)csr[e + 4] << 6) + cb;
        unsigned v0 = *(const unsigned*)(hs + o0);
        unsigned v1 = *(const unsigned*)(hs + o1);
        acc4_fp8(v0, acc);
        acc4_fp8(v1, acc);
    }
    for (; e < end; e += 4) {
        unsigned o = ((unsigned)csr[e] << 6) + cb;
        acc4_fp8(*(const unsigned*)(hs + o), acc);
    }
#pragma unroll
    for (int off = 16; off <= 32; off <<= 1)
#pragma unroll
        for (int i = 0; i < 2; i++) {
            acc[i].x += __shfl_xor(acc[i].x, off);
            acc[i].y += __shfl_xor(acc[i].y, off);
        }
    if (g == 0) {
        floatx2 s[2];
        s[0] = (floatx2)(0.f); s[1] = (floatx2)(0.f);
        acc4_fp8(*(const unsigned*)(hs + (((unsigned)n << 6) + cb)), s);
        float d = dinv[n];
        int j = c * 4;
        float4 b4 = *(const float4*)(bias + j);
        float4 r;
        r.x = (acc[0].x + s[0].x) * d + b4.x;
        r.y = (acc[0].y + s[0].y) * d + b4.y;
        r.z = (acc[1].x + s[1].x) * d + b4.z;
        r.w = (acc[1].y + s[1].y) * d + b4.w;
        *(float4*)(out + (((size_t)n << 6) + j)) = r;
    }
}

// ---------------- fused attention head (64 rows/block, register-tiled phase 1) ----------------
__global__ __launch_bounds__(256) void attn_kernel(const float* __restrict__ h2,
                                                   const float* __restrict__ Wf1,
                                                   const float* __restrict__ bf1,
                                                   const float* __restrict__ Wf2,
                                                   const float* __restrict__ bf2,
                                                   float* __restrict__ att,
                                                   float* __restrict__ colsum) {
    __shared__ float h2S[64][68];
    __shared__ float a1S[64][68];
    __shared__ float colS[8][64];
    int t = threadIdx.x;
    int base = blockIdx.x * 64;
    colS[t >> 6][t & 63] = 0.f;
    colS[(t >> 6) + 4][t & 63] = 0.f;
#pragma unroll
    for (int q = 0; q < 4; q++) {
        int idx = t + q * 256;
        int r = idx >> 4, c = (idx & 15) * 4;
        int row = base + r;
        float4 v = (row < NNODES) ? *(const float4*)(h2 + (size_t)row * 64 + c)
                                  : make_float4(0.f, 0.f, 0.f, 0.f);
        *(float4*)(&h2S[r][c]) = v;
    }
    __syncthreads();
    {
        int cg = t & 15, rg = t >> 4;
        int j = cg * 4, r0 = rg * 4;
        float4 b4 = *(const float4*)(bf1 + j);
        float4 acc[4];
#pragma unroll
        for (int r = 0; r < 4; r++) acc[r] = b4;
#pragma unroll 4
        for (int k = 0; k < 64; k++) {
            float4 w = *(const float4*)(Wf1 + (size_t)k * 64 + j);
#pragma unroll
            for (int r = 0; r < 4; r++) {
                float a = h2S[r0 + r][k];
                acc[r].x += a * w.x; acc[r].y += a * w.y;
                acc[r].z += a * w.z; acc[r].w += a * w.w;
            }
        }
#pragma unroll
        for (int r = 0; r < 4; r++) {
            a1S[r0 + r][j]     = tanhf(acc[r].x);
            a1S[r0 + r][j + 1] = tanhf(acc[r].y);
            a1S[r0 + r][j + 2] = tanhf(acc[r].z);
            a1S[r0 + r][j + 3] = tanhf(acc[r].w);
        }
    }
    __syncthreads();
    {
        int c = t & 7, r = t >> 3;   // r in 0..31
#pragma unroll
        for (int h = 0; h < 2; h++) {
            int rr = r + h * 32;
            float acc = bf2[c];
            for (int k = 0; k < 64; k++)
                acc += a1S[rr][k] * Wf2[(size_t)k * 8 + c];
            int row = base + rr;
            if (row < NNODES) {
                float ev = __expf(acc);
                att[(size_t)row * 8 + c] = ev;
                colS[c][rr] = ev;
            }
        }
    }
    __syncthreads();
    if (t < 8) {
        float s = 0.f;
#pragma unroll
        for (int r = 0; r < 64; r++) s += colS[t][r];
        atomicAdd(colsum + t, s);
    }
}

// ---------------- pooled reductions: ge[8][64] += attU.T@h2 ; ata[8][8] += attU.T@attU ----
__global__ __launch_bounds__(512) void pooled_kernel(const float* __restrict__ att,
                                                     const float* __restrict__ h2,
                                                     float* __restrict__ ge,
                                                     float* __restrict__ ata) {
    __shared__ float attS[64][8];
    __shared__ float h2S[64][64];
    int t = threadIdx.x;
    int d = t >> 6, j = t & 63;
    int de = t >> 3, ee = t & 7;
    float acc = 0.f, acc2 = 0.f;
    int ntiles = (NNODES + 63) / 64;
    for (int tile = blockIdx.x; tile < ntiles; tile += gridDim.x) {
        int base = tile * 64;
        {
            int i = t >> 3, c = t & 7;
            int row = base + i;
            attS[i][c] = (row < NNODES) ? att[(size_t)row * 8 + c] : 0.f;
        }
#pragma unroll
        for (int q = 0; q < 2; q++) {
            int idx = t + q * 512;
            int i = idx >> 4;
            int c = (idx & 15) * 4;
            int row = base + i;
            float4 v = (row < NNODES) ? *(const float4*)(h2 + (size_t)row * 64 + c)
                                      : make_float4(0.f, 0.f, 0.f, 0.f);
            *(float4*)(&h2S[i][c]) = v;
        }
        __syncthreads();
#pragma unroll 8
        for (int i = 0; i < 64; i++) acc += attS[i][d] * h2S[i][j];
        if (t < 64) {
#pragma unroll 8
            for (int i = 0; i < 64; i++) acc2 += attS[i][de] * attS[i][ee];
        }
        __syncthreads();
    }
    atomicAdd(ge + d * 64 + j, acc);
    if (t < 64) atomicAdd(ata + de * 8 + ee, acc2);
}

// ---------------- tiny epilogue ----------------
__global__ void final_kernel(const float* __restrict__ geacc, const float* __restrict__ ata,
                             const float* __restrict__ colsum, const float* __restrict__ Wl,
                             const float* __restrict__ bl, float* __restrict__ out) {
    __shared__ float geF[512];
    __shared__ float inv[8];
    __shared__ float logits[10];
    int t = threadIdx.x;
    if (t < 8) inv[t] = 1.0f / colsum[t];
    __syncthreads();
    for (int idx = t; idx < 512; idx += 64) {
        int d = idx >> 6;
        float v = geacc[idx] * inv[d];
        geF[idx] = v;
        out[idx] = v;                       // graph_embedding
    }
    __syncthreads();
    if (t == 0) {
        float pen = 0.f;
        for (int d = 0; d < 8; d++) {
            float s = 0.f;
            for (int e = 0; e < 8; e++) {
                float p = ata[d * 8 + e] * inv[d] * inv[e] - (d == e ? 1.0f : 0.0f);
                s += p * p;
            }
            pen += sqrtf(s);
        }
        out[512] = pen;                     // penalty
    }
    if (t < 10) {
        float acc = bl[t];
        for (int k = 0; k < 512; k++) acc += geF[k] * Wl[(size_t)k * 10 + t];
        logits[t] = acc;
    }
    __syncthreads();
    if (t == 0) {
        float m = -INFINITY;
        for (int l = 0; l < 10; l++) m = fmaxf(m, logits[l]);
        float s = 0.f;
        for (int l = 0; l < 10; l++) s += expf(logits[l] - m);
        float ls = logf(s);
        for (int l = 0; l < 10; l++) out[513 + l] = logits[l] - m - ls;  // log_softmax
    }
}

extern "C" void kernel_launch(void* const* d_in, const int* in_sizes, int n_in,
                              void* d_out, int out_size, void* d_ws, size_t ws_size,
                              hipStream_t stream) {
    const int* esrc = (const int*)d_in[0];
    const int* edst = esrc + NEDGES;
    const float* X   = (const float*)d_in[1];
    const float* W1  = (const float*)d_in[2];
    const float* b1  = (const float*)d_in[3];
    const float* W2  = (const float*)d_in[4];
    const float* b2  = (const float*)d_in[5];
    const float* Wf1 = (const float*)d_in[6];
    const float* bf1 = (const float*)d_in[7];
    const float* Wf2 = (const float*)d_in[8];
    const float* bf2 = (const float*)d_in[9];
    const float* Wl  = (const float*)d_in[10];
    const float* bl  = (const float*)d_in[11];
    float* out = (float*)d_out;

    // workspace layout
    float* ws     = (float*)d_ws;
    float* dinv   = ws;                               // N (padded to 100352)
    float* smalls = ws + 100352;                      // 1024
    float* colsum = smalls + 8;                       // 8
    float* ata    = smalls + 16;                      // 64
    float* geacc  = smalls + 80;                      // 512
    float* A = ws + 101376;                           // N*128 fp32 region
    float* B = A + (size_t)NNODES * 128;              // N*128 fp32 region
    int* row_start = (int*)(B + (size_t)NNODES * 128);// N+1 (padded 100352)
    int* btot      = row_start + 100352;              // NBUK (padded 1024)
    int* bstart    = btot + 1024;                     // NBUK+1 (padded 1024)
    int* csr       = bstart + 1024;                   // E
    int* ebuk      = (int*)A;                         // E temp (consumed before gemm1 writes A)
    int* hist      = (int*)B;                         // NCHUNK*NBUK temp (consumed before gather128 writes B)
    unsigned char* stage = (unsigned char*)A;         // fp8 staging (N*128 or N*64 bytes)
    unsigned short* h1 = (unsigned short*)B;          // N*128 bf16
    float* h2  = B;                                   // N*64 fp32 (overwrites h1 after gemm2 consumed it)
    float* L   = A;                                   // N*8 fp32 (att, after stage2 consumed)

    // ---- CSR build + dinv (deterministic two-pass counting sort) ----
    chunk_hist_kernel<<<NCHUNK, 1024, 0, stream>>>(edst, hist);
    col_scan_kernel<<<4, 256, 0, stream>>>(hist, btot);
    bucket_scan_kernel<<<1, 1024, 0, stream>>>(btot, bstart, row_start, smalls);
    chunk_scatter_kernel<<<NCHUNK, 1024, 0, stream>>>(esrc, edst, hist, bstart, ebuk);
    build_kernel<<<NBUK, 256, 0, stream>>>(ebuk, bstart, row_start, dinv, csr);

    // ---- GCN layer 1: stage = fp8(dinv*(X@W1)); h1(bf16) = relu(gather(stage)*dinv + b1) ----
    gemm_stage_kernel<128, 128, 64><<<(NNODES + 63) / 64, 256, 0, stream>>>(X, W1, dinv, stage, NNODES);
    gather128_kernel<<<(NNODES + 3) / 4, 256, 0, stream>>>(stage, row_start, csr, dinv, b1, h1);

    // ---- GCN layer 2: stage = fp8(dinv*(h1@W2)); h2 = gather(stage)*dinv + b2 ----
    gemm_stage_bf16_kernel<128, 64, 64><<<(NNODES + 63) / 64, 256, 0, stream>>>(h1, W2, dinv, stage, NNODES);
    gather64_kernel<<<(NNODES + 3) / 4, 256, 0, stream>>>(stage, row_start, csr, dinv, b2, h2);

    // ---- fused attention head: att(L) = exp(tanh(h2@Wf1+bf1)@Wf2+bf2), colsum ----
    attn_kernel<<<(NNODES + 63) / 64, 256, 0, stream>>>(h2, Wf1, bf1, Wf2, bf2, L, colsum);

    // ---- pooling + epilogue ----
    pooled_kernel<<<512, 512, 0, stream>>>(L, h2, geacc, ata);
    final_kernel<<<1, 64, 0, stream>>>(geacc, ata, colsum, Wl, bl, out);
}

// Round 9
// 496.180 us; speedup vs baseline: 1.0352x; 1.0352x over previous
//
#include <hip/hip_runtime.h>
#include <hip/hip_bf16.h>
#include <math.h>

#define NNODES 100000
#define NEDGES 3200000
#define NBUK ((NNODES + 127) >> 7)   // 782 buckets of 128 nodes
#define NCHUNK 128
#define EPC (NEDGES / NCHUNK)        // 25000 edges per chunk

typedef float floatx2 __attribute__((ext_vector_type(2)));

// ---- bf16 pack/unpack ----
__device__ __forceinline__ unsigned short f2bf(float x) {
    unsigned u = __float_as_uint(x);
    unsigned r = u + 0x7FFFu + ((u >> 16) & 1u);
    return (unsigned short)(r >> 16);
}
__device__ __forceinline__ void unpack8_bf16(uint4 v, float* f) {
    f[0] = __uint_as_float(v.x << 16); f[1] = __uint_as_float(v.x & 0xFFFF0000u);
    f[2] = __uint_as_float(v.y << 16); f[3] = __uint_as_float(v.y & 0xFFFF0000u);
    f[4] = __uint_as_float(v.z << 16); f[5] = __uint_as_float(v.z & 0xFFFF0000u);
    f[6] = __uint_as_float(v.w << 16); f[7] = __uint_as_float(v.w & 0xFFFF0000u);
}

// ---- fp8 e4m3 packed accumulate (gfx950 HW converts) ----
__device__ __forceinline__ void acc8_fp8(uint2 v, floatx2* a) {
    a[0] += __builtin_amdgcn_cvt_pk_f32_fp8(v.x, false);
    a[1] += __builtin_amdgcn_cvt_pk_f32_fp8(v.x, true);
    a[2] += __builtin_amdgcn_cvt_pk_f32_fp8(v.y, false);
    a[3] += __builtin_amdgcn_cvt_pk_f32_fp8(v.y, true);
}
__device__ __forceinline__ void acc4_fp8(unsigned v, floatx2* a) {
    a[0] += __builtin_amdgcn_cvt_pk_f32_fp8(v, false);
    a[1] += __builtin_amdgcn_cvt_pk_f32_fp8(v, true);
}

// ---------------- pass 1: per-chunk bucket histogram (LDS) ----------------
__global__ __launch_bounds__(1024) void chunk_hist_kernel(const int* __restrict__ dst,
                                                          int* __restrict__ hist) {
    __shared__ int h[NBUK];
    int c = blockIdx.x, t = threadIdx.x;
    for (int i = t; i < NBUK; i += 1024) h[i] = 0;
    __syncthreads();
    int e0 = c * EPC, e1 = e0 + EPC;
    for (int e = e0 + t; e < e1; e += 1024)
        atomicAdd(&h[dst[e] >> 7], 1);
    __syncthreads();
    for (int i = t; i < NBUK; i += 1024)
        hist[c * NBUK + i] = h[i];
}

// ---------------- pass 2: per-bucket exclusive prefix over chunks ----------------
__global__ void col_scan_kernel(int* __restrict__ hist, int* __restrict__ btot) {
    int t = blockIdx.x * 256 + threadIdx.x;
    if (t >= NBUK) return;
    int run = 0;
    for (int c = 0; c < NCHUNK; c++) {
        int idx = c * NBUK + t;
        int v = hist[idx];
        hist[idx] = run;
        run += v;
    }
    btot[t] = run;
}

// ---------------- pass 3: scan bucket totals -> bstart; zero small accumulators ----------------
__global__ void bucket_scan_kernel(const int* __restrict__ btot, int* __restrict__ bstart,
                                   int* __restrict__ row_start, float* __restrict__ smalls) {
    __shared__ int s[1024];
    int t = threadIdx.x;
    if (t < 592) smalls[t] = 0.0f;   // colsum(8) ata(64) ge(512)
    int v = (t < NBUK) ? btot[t] : 0;
    s[t] = v;
    __syncthreads();
    for (int off = 1; off < 1024; off <<= 1) {
        int x = (t >= off) ? s[t - off] : 0;
        __syncthreads();
        s[t] += x;
        __syncthreads();
    }
    if (t < NBUK) bstart[t] = s[t] - v;
    if (t == 0) {
        bstart[NBUK] = NEDGES;
        row_start[NNODES] = NEDGES;
    }
}

// ---------------- pass 4: deterministic scatter into bucket order (LDS cursors) ----------------
__global__ __launch_bounds__(1024) void chunk_scatter_kernel(const int* __restrict__ src,
                                                             const int* __restrict__ dst,
                                                             const int* __restrict__ hist,
                                                             const int* __restrict__ bstart,
                                                             int* __restrict__ ebuk) {
    __shared__ int cur[NBUK];
    int c = blockIdx.x, t = threadIdx.x;
    for (int i = t; i < NBUK; i += 1024)
        cur[i] = bstart[i] + hist[c * NBUK + i];
    __syncthreads();
    int e0 = c * EPC, e1 = e0 + EPC;
    for (int e = e0 + t; e < e1; e += 1024) {
        int d = dst[e];
        int pos = atomicAdd(&cur[d >> 7], 1);
        ebuk[pos] = src[e] | ((d & 127) << 20);   // src < 2^17 fits in 20 bits
    }
}

// ---------------- per-bucket: node counts, row_start, dinv, csr fill ----------------
__global__ __launch_bounds__(256) void build_kernel(const int* __restrict__ ebuk,
                                                    const int* __restrict__ bstart,
                                                    int* __restrict__ row_start,
                                                    float* __restrict__ dinv,
                                                    int* __restrict__ csr) {
    __shared__ int cnt[128];
    __shared__ int cur[128];
    int b = blockIdx.x;
    int t = threadIdx.x;
    int s0 = bstart[b], s1 = bstart[b + 1];
    if (t < 128) cnt[t] = 0;
    __syncthreads();
    for (int i = s0 + t; i < s1; i += 256)
        atomicAdd(&cnt[(ebuk[i] >> 20) & 127], 1);
    __syncthreads();
    if (t == 0) {
        int run = s0;
        for (int i = 0; i < 128; i++) { cur[i] = run; run += cnt[i]; }
    }
    __syncthreads();
    int node = b * 128 + t;
    if (t < 128 && node < NNODES) {
        row_start[node] = cur[t];
        dinv[node] = rsqrtf((float)cnt[t] + 1.0f);
    }
    __syncthreads();
    for (int i = s0 + t; i < s1; i += 256) {
        int v = ebuk[i];
        int pos = atomicAdd(&cur[(v >> 20) & 127], 1);
        csr[pos] = v & 0xFFFFF;
    }
}

// ---------------- register-tiled GEMM (fp32 A): stage(fp8) = rowscale * (A @ W) ----------------
template <int KIN, int KOUT, int TR>
__global__ __launch_bounds__(256) void gemm_stage_kernel(const float* __restrict__ A,
                                                         const float* __restrict__ W,
                                                         const float* __restrict__ rowscale,
                                                         unsigned char* __restrict__ stage,
                                                         int nrows) {
    constexpr int COLG = KOUT / 4;
    constexpr int ROWG = 256 / COLG;
    constexpr int R    = TR / ROWG;
    constexpr int LDK  = KIN + 4;
    __shared__ float As[TR][LDK];
    int block_row = blockIdx.x * TR;
    int tid = threadIdx.x;

    constexpr int C4 = KIN / 4;
    for (int idx = tid; idx < TR * C4; idx += 256) {
        int r = idx / C4, c = idx % C4;
        float4 v = make_float4(0.f, 0.f, 0.f, 0.f);
        if (block_row + r < nrows)
            v = *(const float4*)(A + (size_t)(block_row + r) * KIN + c * 4);
        *(float4*)(&As[r][c * 4]) = v;
    }
    __syncthreads();

    int cg = tid % COLG, rg = tid / COLG;
    int j  = cg * 4;
    int r0 = rg * R;
    float4 acc[R];
#pragma unroll
    for (int r = 0; r < R; r++) acc[r] = make_float4(0.f, 0.f, 0.f, 0.f);

#pragma unroll 4
    for (int k = 0; k < KIN; k++) {
        float4 w = *(const float4*)(W + (size_t)k * KOUT + j);
#pragma unroll
        for (int r = 0; r < R; r++) {
            float a = As[r0 + r][k];
            acc[r].x += a * w.x; acc[r].y += a * w.y;
            acc[r].z += a * w.z; acc[r].w += a * w.w;
        }
    }
#pragma unroll
    for (int r = 0; r < R; r++) {
        int row = block_row + r0 + r;
        if (row < nrows) {
            float d = rowscale[row];
            int pk = __builtin_amdgcn_cvt_pk_fp8_f32(acc[r].x * d, acc[r].y * d, 0, false);
            pk = __builtin_amdgcn_cvt_pk_fp8_f32(acc[r].z * d, acc[r].w * d, pk, true);
            *(unsigned*)(stage + (size_t)row * KOUT + j) = (unsigned)pk;
        }
    }
}

// ---------------- register-tiled GEMM (bf16 A): stage(fp8) = rowscale * (A @ W) ----------------
template <int KIN, int KOUT, int TR>
__global__ __launch_bounds__(256) void gemm_stage_bf16_kernel(const unsigned short* __restrict__ A,
                                                              const float* __restrict__ W,
                                                              const float* __restrict__ rowscale,
                                                              unsigned char* __restrict__ stage,
                                                              int nrows) {
    constexpr int COLG = KOUT / 4;
    constexpr int ROWG = 256 / COLG;
    constexpr int R    = TR / ROWG;
    constexpr int LDK  = KIN + 4;
    __shared__ float As[TR][LDK];
    int block_row = blockIdx.x * TR;
    int tid = threadIdx.x;

    constexpr int C8 = KIN / 8;
    for (int idx = tid; idx < TR * C8; idx += 256) {
        int r = idx / C8, c = idx % C8;
        float f[8];
        uint4 v = make_uint4(0, 0, 0, 0);
        if (block_row + r < nrows)
            v = *(const uint4*)(A + (size_t)(block_row + r) * KIN + c * 8);
        unpack8_bf16(v, f);
#pragma unroll
        for (int i = 0; i < 8; i++) As[r][c * 8 + i] = f[i];
    }
    __syncthreads();

    int cg = tid % COLG, rg = tid / COLG;
    int j  = cg * 4;
    int r0 = rg * R;
    float4 acc[R];
#pragma unroll
    for (int r = 0; r < R; r++) acc[r] = make_float4(0.f, 0.f, 0.f, 0.f);

#pragma unroll 4
    for (int k = 0; k < KIN; k++) {
        float4 w = *(const float4*)(W + (size_t)k * KOUT + j);
#pragma unroll
        for (int r = 0; r < R; r++) {
            float a = As[r0 + r][k];
            acc[r].x += a * w.x; acc[r].y += a * w.y;
            acc[r].z += a * w.z; acc[r].w += a * w.w;
        }
    }
#pragma unroll
    for (int r = 0; r < R; r++) {
        int row = block_row + r0 + r;
        if (row < nrows) {
            float d = rowscale[row];
            int pk = __builtin_amdgcn_cvt_pk_fp8_f32(acc[r].x * d, acc[r].y * d, 0, false);
            pk = __builtin_amdgcn_cvt_pk_fp8_f32(acc[r].z * d, acc[r].w * d, pk, true);
            *(unsigned*)(stage + (size_t)row * KOUT + j) = (unsigned)pk;
        }
    }
}

// ---------------- gather K=128 fp8: 4 groups x 16 lanes; 16-edge windows, int4 csr, 4-deep MLP ----
__global__ __launch_bounds__(256) void gather128_kernel(
    const unsigned char* __restrict__ hs, const int* __restrict__ row_start,
    const int* __restrict__ csr, const float* __restrict__ dinv,
    const float* __restrict__ bias, unsigned short* __restrict__ out) {
    int wave = threadIdx.x >> 6;
    int lane = threadIdx.x & 63;
    int n = blockIdx.x * 4 + wave;
    if (n >= NNODES) return;
    int g = lane >> 4;          // 0..3: edge sub-group
    int c = lane & 15;          // uint2 index within 128 B row
    unsigned cb = (unsigned)c << 3;
    int start = row_start[n], end = row_start[n + 1];
    floatx2 acc[4];
#pragma unroll
    for (int i = 0; i < 4; i++) acc[i] = (floatx2)(0.f);
    int w = (start + 3) & ~3;
    if (w > end) w = end;
    {   // prologue: edges [start, w)
        int e2 = start + g;
        if (e2 < w) {
            unsigned o = ((unsigned)csr[e2] << 7) + cb;
            acc8_fp8(*(const uint2*)(hs + o), acc);
        }
    }
    for (; w + 16 <= end; w += 16) {          // aligned 16-edge windows
        int4 cs = *(const int4*)(csr + w + 4 * g);
        unsigned o0 = ((unsigned)cs.x << 7) + cb;
        unsigned o1 = ((unsigned)cs.y << 7) + cb;
        unsigned o2 = ((unsigned)cs.z << 7) + cb;
        unsigned o3 = ((unsigned)cs.w << 7) + cb;
        uint2 v0 = *(const uint2*)(hs + o0);
        uint2 v1 = *(const uint2*)(hs + o1);
        uint2 v2 = *(const uint2*)(hs + o2);
        uint2 v3 = *(const uint2*)(hs + o3);
        acc8_fp8(v0, acc);
        acc8_fp8(v1, acc);
        acc8_fp8(v2, acc);
        acc8_fp8(v3, acc);
    }
    for (int e2 = w + g; e2 < end; e2 += 4) {  // epilogue
        unsigned o = ((unsigned)csr[e2] << 7) + cb;
        acc8_fp8(*(const uint2*)(hs + o), acc);
    }
#pragma unroll
    for (int off = 16; off <= 32; off <<= 1)
#pragma unroll
        for (int i = 0; i < 4; i++) {
            acc[i].x += __shfl_xor(acc[i].x, off);
            acc[i].y += __shfl_xor(acc[i].y, off);
        }
    if (g == 0) {
        floatx2 s[4];
#pragma unroll
        for (int i = 0; i < 4; i++) s[i] = (floatx2)(0.f);
        acc8_fp8(*(const uint2*)(hs + (((unsigned)n << 7) + cb)), s);
        float d = dinv[n];
        int j = c * 8;
        float4 b0 = *(const float4*)(bias + j);
        float4 b1 = *(const float4*)(bias + j + 4);
        float r0 = fmaxf((acc[0].x + s[0].x) * d + b0.x, 0.f);
        float r1 = fmaxf((acc[0].y + s[0].y) * d + b0.y, 0.f);
        float r2 = fmaxf((acc[1].x + s[1].x) * d + b0.z, 0.f);
        float r3 = fmaxf((acc[1].y + s[1].y) * d + b0.w, 0.f);
        float r4 = fmaxf((acc[2].x + s[2].x) * d + b1.x, 0.f);
        float r5 = fmaxf((acc[2].y + s[2].y) * d + b1.y, 0.f);
        float r6 = fmaxf((acc[3].x + s[3].x) * d + b1.z, 0.f);
        float r7 = fmaxf((acc[3].y + s[3].y) * d + b1.w, 0.f);
        uint4 p;
        p.x = (unsigned)f2bf(r0) | ((unsigned)f2bf(r1) << 16);
        p.y = (unsigned)f2bf(r2) | ((unsigned)f2bf(r3) << 16);
        p.z = (unsigned)f2bf(r4) | ((unsigned)f2bf(r5) << 16);
        p.w = (unsigned)f2bf(r6) | ((unsigned)f2bf(r7) << 16);
        *(uint4*)(out + (((size_t)n << 7) + j)) = p;
    }
}

// ---------------- gather K=64 fp8: 4 groups x 16 lanes; 16-edge windows, int4 csr ----------------
__global__ __launch_bounds__(256) void gather64_kernel(
    const unsigned char* __restrict__ hs, const int* __restrict__ row_start,
    const int* __restrict__ csr, const float* __restrict__ dinv,
    const float* __restrict__ bias, float* __restrict__ out) {
    int wave = threadIdx.x >> 6;
    int lane = threadIdx.x & 63;
    int n = blockIdx.x * 4 + wave;
    if (n >= NNODES) return;
    int g = lane >> 4;          // 0..3: edge sub-group
    int c = lane & 15;          // uint index within 64 B row
    unsigned cb = (unsigned)c << 2;
    int start = row_start[n], end = row_start[n + 1];
    floatx2 acc[2];
    acc[0] = (floatx2)(0.f); acc[1] = (floatx2)(0.f);
    int w = (start + 3) & ~3;
    if (w > end) w = end;
    {
        int e2 = start + g;
        if (e2 < w) {
            unsigned o = ((unsigned)csr[e2] << 6) + cb;
            acc4_fp8(*(const unsigned*)(hs + o), acc);
        }
    }
    for (; w + 16 <= end; w += 16) {
        int4 cs = *(const int4*)(csr + w + 4 * g);
        unsigned o0 = ((unsigned)cs.x << 6) + cb;
        unsigned o1 = ((unsigned)cs.y << 6) + cb;
        unsigned o2 = ((unsigned)cs.z << 6) + cb;
        unsigned o3 = ((unsigned)cs.w << 6) + cb;
        unsigned v0 = *(const unsigned*)(hs + o0);
        unsigned v1 = *(const unsigned*)(hs + o1);
        unsigned v2 = *(const unsigned*)(hs + o2);
        unsigned v3 = *(const unsigned*)(hs + o3);
        acc4_fp8(v0, acc);
        acc4_fp8(v1, acc);
        acc4_fp8(v2, acc);
        acc4_fp8(v3, acc);
    }
    for (int e2 = w + g; e2 < end; e2 += 4) {
        unsigned o = ((unsigned)csr[e2] << 6) + cb;
        acc4_fp8(*(const unsigned*)(hs + o), acc);
    }
#pragma unroll
    for (int off = 16; off <= 32; off <<= 1)
#pragma unroll
        for (int i = 0; i < 2; i++) {
            acc[i].x += __shfl_xor(acc[i].x, off);
            acc[i].y += __shfl_xor(acc[i].y, off);
        }
    if (g == 0) {
        floatx2 s[2];
        s[0] = (floatx2)(0.f); s[1] = (floatx2)(0.f);
        acc4_fp8(*(const unsigned*)(hs + (((unsigned)n << 6) + cb)), s);
        float d = dinv[n];
        int j = c * 4;
        float4 b4 = *(const float4*)(bias + j);
        float4 r;
        r.x = (acc[0].x + s[0].x) * d + b4.x;
        r.y = (acc[0].y + s[0].y) * d + b4.y;
        r.z = (acc[1].x + s[1].x) * d + b4.z;
        r.w = (acc[1].y + s[1].y) * d + b4.w;
        *(float4*)(out + (((size_t)n << 6) + j)) = r;
    }
}

// ---------------- fused attention + pooling (grid-stride over 64-row tiles) ----------------
// Per tile: a1 = tanh(h2@Wf1+bf1); att = exp(a1@Wf2+bf2) kept in LDS; accumulate
// ge += att^T h2, ata += att^T att, colsum += column sums. One atomic batch per block.
__global__ __launch_bounds__(256) void attnpool_kernel(const float* __restrict__ h2,
                                                       const float* __restrict__ Wf1,
                                                       const float* __restrict__ bf1,
                                                       const float* __restrict__ Wf2,
                                                       const float* __restrict__ bf2,
                                                       float* __restrict__ ge,
                                                       float* __restrict__ ata,
                                                       float* __restrict__ colsum) {
    __shared__ float h2S[64][68];
    __shared__ float a1S[64][68];
    __shared__ float attS[64][8];
    __shared__ float colS[8][64];
    int t = threadIdx.x;
    int d0 = t >> 6;            // 0..3 (covers d and d+4)
    int j  = t & 63;
    int de = t >> 3, ee = t & 7;  // for t<64 (ata)
    float accge0 = 0.f, accge1 = 0.f, accata = 0.f, acccol = 0.f;
    int ntiles = (NNODES + 63) / 64;
    for (int tile = blockIdx.x; tile < ntiles; tile += gridDim.x) {
        int base = tile * 64;
#pragma unroll
        for (int q = 0; q < 4; q++) {
            int idx = t + q * 256;
            int r = idx >> 4, cc = (idx & 15) * 4;
            int row = base + r;
            float4 v = (row < NNODES) ? *(const float4*)(h2 + (size_t)row * 64 + cc)
                                      : make_float4(0.f, 0.f, 0.f, 0.f);
            *(float4*)(&h2S[r][cc]) = v;
        }
        __syncthreads();
        {   // phase 1: a1 = tanh(h2 @ Wf1 + bf1); 4 rows x 4 cols per thread
            int cg = t & 15, rg = t >> 4;
            int jj = cg * 4, r0 = rg * 4;
            float4 b4 = *(const float4*)(bf1 + jj);
            float4 acc[4];
#pragma unroll
            for (int r = 0; r < 4; r++) acc[r] = b4;
#pragma unroll 4
            for (int k = 0; k < 64; k++) {
                float4 wv = *(const float4*)(Wf1 + (size_t)k * 64 + jj);
#pragma unroll
                for (int r = 0; r < 4; r++) {
                    float a = h2S[r0 + r][k];
                    acc[r].x += a * wv.x; acc[r].y += a * wv.y;
                    acc[r].z += a * wv.z; acc[r].w += a * wv.w;
                }
            }
#pragma unroll
            for (int r = 0; r < 4; r++) {
                a1S[r0 + r][jj]     = tanhf(acc[r].x);
                a1S[r0 + r][jj + 1] = tanhf(acc[r].y);
                a1S[r0 + r][jj + 2] = tanhf(acc[r].z);
                a1S[r0 + r][jj + 3] = tanhf(acc[r].w);
            }
        }
        __syncthreads();
        {   // phase 2: att = exp(a1 @ Wf2 + bf2), stay in LDS
            int cc = t & 7, r = t >> 3;   // r in 0..31
#pragma unroll
            for (int h = 0; h < 2; h++) {
                int rr = r + h * 32;
                float acc = bf2[cc];
                for (int k = 0; k < 64; k++)
                    acc += a1S[rr][k] * Wf2[(size_t)k * 8 + cc];
                float ev = (base + rr < NNODES) ? __expf(acc) : 0.f;
                attS[rr][cc] = ev;
                colS[cc][rr] = ev;
            }
        }
        __syncthreads();
        // pooled accumulation
#pragma unroll 8
        for (int i = 0; i < 64; i++) {
            float hv = h2S[i][j];
            accge0 += attS[i][d0] * hv;
            accge1 += attS[i][d0 + 4] * hv;
        }
        if (t < 64) {
#pragma unroll 8
            for (int i = 0; i < 64; i++) accata += attS[i][de] * attS[i][ee];
        }
        if (t < 8) {
            float s = 0.f;
#pragma unroll
            for (int r = 0; r < 64; r++) s += colS[t][r];
            acccol += s;
        }
        __syncthreads();
    }
    atomicAdd(ge + d0 * 64 + j, accge0);
    atomicAdd(ge + (d0 + 4) * 64 + j, accge1);
    if (t < 64) atomicAdd(ata + de * 8 + ee, accata);
    if (t < 8) atomicAdd(colsum + t, acccol);
}

// ---------------- tiny epilogue ----------------
__global__ void final_kernel(const float* __restrict__ geacc, const float* __restrict__ ata,
                             const float* __restrict__ colsum, const float* __restrict__ Wl,
                             const float* __restrict__ bl, float* __restrict__ out) {
    __shared__ float geF[512];
    __shared__ float inv[8];
    __shared__ float logits[10];
    int t = threadIdx.x;
    if (t < 8) inv[t] = 1.0f / colsum[t];
    __syncthreads();
    for (int idx = t; idx < 512; idx += 64) {
        int d = idx >> 6;
        float v = geacc[idx] * inv[d];
        geF[idx] = v;
        out[idx] = v;                       // graph_embedding
    }
    __syncthreads();
    if (t == 0) {
        float pen = 0.f;
        for (int d = 0; d < 8; d++) {
            float s = 0.f;
            for (int e = 0; e < 8; e++) {
                float p = ata[d * 8 + e] * inv[d] * inv[e] - (d == e ? 1.0f : 0.0f);
                s += p * p;
            }
            pen += sqrtf(s);
        }
        out[512] = pen;                     // penalty
    }
    if (t < 10) {
        float acc = bl[t];
        for (int k = 0; k < 512; k++) acc += geF[k] * Wl[(size_t)k * 10 + t];
        logits[t] = acc;
    }
    __syncthreads();
    if (t == 0) {
        float m = -INFINITY;
        for (int l = 0; l < 10; l++) m = fmaxf(m, logits[l]);
        float s = 0.f;
        for (int l = 0; l < 10; l++) s += expf(logits[l] - m);
        float ls = logf(s);
        for (int l = 0; l < 10; l++) out[513 + l] = logits[l] - m - ls;  // log_softmax
    }
}

extern "C" void kernel_launch(void* const* d_in, const int* in_sizes, int n_in,
                              void* d_out, int out_size, void* d_ws, size_t ws_size,
                              hipStream_t stream) {
    const int* esrc = (const int*)d_in[0];
    const int* edst = esrc + NEDGES;
    const float* X   = (const float*)d_in[1];
    const float* W1  = (const float*)d_in[2];
    const float* b1  = (const float*)d_in[3];
    const float* W2  = (const float*)d_in[4];
    const float* b2  = (const float*)d_in[5];
    const float* Wf1 = (const float*)d_in[6];
    const float* bf1 = (const float*)d_in[7];
    const float* Wf2 = (const float*)d_in[8];
    const float* bf2 = (const float*)d_in[9];
    const float* Wl  = (const float*)d_in[10];
    const float* bl  = (const float*)d_in[11];
    float* out = (float*)d_out;

    // workspace layout
    float* ws     = (float*)d_ws;
    float* dinv   = ws;                               // N (padded to 100352)
    float* smalls = ws + 100352;                      // 1024
    float* colsum = smalls + 8;                       // 8
    float* ata    = smalls + 16;                      // 64
    float* geacc  = smalls + 80;                      // 512
    float* A = ws + 101376;                           // N*128 fp32 region
    float* B = A + (size_t)NNODES * 128;              // N*128 fp32 region
    int* row_start = (int*)(B + (size_t)NNODES * 128);// N+1 (padded 100352)
    int* btot      = row_start + 100352;              // NBUK (padded 1024)
    int* bstart    = btot + 1024;                     // NBUK+1 (padded 1024)
    int* csr       = bstart + 1024;                   // E
    int* ebuk      = (int*)A;                         // E temp (consumed before gemm1 writes A)
    int* hist      = (int*)B;                         // NCHUNK*NBUK temp (consumed before gather128 writes B)
    unsigned char* stage = (unsigned char*)A;         // fp8 staging (N*128 or N*64 bytes)
    unsigned short* h1 = (unsigned short*)B;          // N*128 bf16
    float* h2  = B;                                   // N*64 fp32 (overwrites h1 after gemm2 consumed it)

    // ---- CSR build + dinv (deterministic two-pass counting sort) ----
    chunk_hist_kernel<<<NCHUNK, 1024, 0, stream>>>(edst, hist);
    col_scan_kernel<<<4, 256, 0, stream>>>(hist, btot);
    bucket_scan_kernel<<<1, 1024, 0, stream>>>(btot, bstart, row_start, smalls);
    chunk_scatter_kernel<<<NCHUNK, 1024, 0, stream>>>(esrc, edst, hist, bstart, ebuk);
    build_kernel<<<NBUK, 256, 0, stream>>>(ebuk, bstart, row_start, dinv, csr);

    // ---- GCN layer 1: stage = fp8(dinv*(X@W1)); h1(bf16) = relu(gather(stage)*dinv + b1) ----
    gemm_stage_kernel<128, 128, 64><<<(NNODES + 63) / 64, 256, 0, stream>>>(X, W1, dinv, stage, NNODES);
    gather128_kernel<<<(NNODES + 3) / 4, 256, 0, stream>>>(stage, row_start, csr, dinv, b1, h1);

    // ---- GCN layer 2: stage = fp8(dinv*(h1@W2)); h2 = gather(stage)*dinv + b2 ----
    gemm_stage_bf16_kernel<128, 64, 64><<<(NNODES + 63) / 64, 256, 0, stream>>>(h1, W2, dinv, stage, NNODES);
    gather64_kernel<<<(NNODES + 3) / 4, 256, 0, stream>>>(stage, row_start, csr, dinv, b2, h2);

    // ---- fused attention + pooling ----
    attnpool_kernel<<<512, 256, 0, stream>>>(h2, Wf1, bf1, Wf2, bf2, geacc, ata, colsum);
    final_kernel<<<1, 64, 0, stream>>>(geacc, ata, colsum, Wl, bl, out);
}

// Round 10
// 489.529 us; speedup vs baseline: 1.0492x; 1.0136x over previous
//
#include <hip/hip_runtime.h>
#include <hip/hip_bf16.h>
#include <math.h>

#define NNODES 100000
#define NEDGES 3200000
#define NBUK ((NNODES + 127) >> 7)   // 782 buckets of 128 nodes
#define NCHUNK 256
#define EPC (NEDGES / NCHUNK)        // 12500 edges per chunk

typedef float floatx2 __attribute__((ext_vector_type(2)));

// ---- bf16 pack/unpack ----
__device__ __forceinline__ unsigned short f2bf(float x) {
    unsigned u = __float_as_uint(x);
    unsigned r = u + 0x7FFFu + ((u >> 16) & 1u);
    return (unsigned short)(r >> 16);
}
__device__ __forceinline__ void unpack8_bf16(uint4 v, float* f) {
    f[0] = __uint_as_float(v.x << 16); f[1] = __uint_as_float(v.x & 0xFFFF0000u);
    f[2] = __uint_as_float(v.y << 16); f[3] = __uint_as_float(v.y & 0xFFFF0000u);
    f[4] = __uint_as_float(v.z << 16); f[5] = __uint_as_float(v.z & 0xFFFF0000u);
    f[6] = __uint_as_float(v.w << 16); f[7] = __uint_as_float(v.w & 0xFFFF0000u);
}

// ---- fp8 e4m3 packed accumulate (gfx950 HW converts) ----
__device__ __forceinline__ void acc8_fp8(uint2 v, floatx2* a) {
    a[0] += __builtin_amdgcn_cvt_pk_f32_fp8(v.x, false);
    a[1] += __builtin_amdgcn_cvt_pk_f32_fp8(v.x, true);
    a[2] += __builtin_amdgcn_cvt_pk_f32_fp8(v.y, false);
    a[3] += __builtin_amdgcn_cvt_pk_f32_fp8(v.y, true);
}
__device__ __forceinline__ void acc4_fp8(unsigned v, floatx2* a) {
    a[0] += __builtin_amdgcn_cvt_pk_f32_fp8(v, false);
    a[1] += __builtin_amdgcn_cvt_pk_f32_fp8(v, true);
}

// ---------------- pass 1: per-chunk bucket histogram (LDS) ----------------
__global__ __launch_bounds__(1024) void chunk_hist_kernel(const int* __restrict__ dst,
                                                          int* __restrict__ hist) {
    __shared__ int h[NBUK];
    int c = blockIdx.x, t = threadIdx.x;
    for (int i = t; i < NBUK; i += 1024) h[i] = 0;
    __syncthreads();
    int e0 = c * EPC, e1 = e0 + EPC;
    for (int e = e0 + t; e < e1; e += 1024)
        atomicAdd(&h[dst[e] >> 7], 1);
    __syncthreads();
    for (int i = t; i < NBUK; i += 1024)
        hist[c * NBUK + i] = h[i];
}

// ---------------- pass 2: per-bucket exclusive prefix over chunks ----------------
__global__ void col_scan_kernel(int* __restrict__ hist, int* __restrict__ btot) {
    int t = blockIdx.x * 256 + threadIdx.x;
    if (t >= NBUK) return;
    int run = 0;
    for (int c = 0; c < NCHUNK; c++) {
        int idx = c * NBUK + t;
        int v = hist[idx];
        hist[idx] = run;
        run += v;
    }
    btot[t] = run;
}

// ---------------- pass 3: scan bucket totals -> bstart; zero small accumulators ----------------
__global__ void bucket_scan_kernel(const int* __restrict__ btot, int* __restrict__ bstart,
                                   int* __restrict__ row_start, float* __restrict__ smalls) {
    __shared__ int s[1024];
    int t = threadIdx.x;
    if (t < 592) smalls[t] = 0.0f;   // colsum(8) ata(64) ge(512)
    int v = (t < NBUK) ? btot[t] : 0;
    s[t] = v;
    __syncthreads();
    for (int off = 1; off < 1024; off <<= 1) {
        int x = (t >= off) ? s[t - off] : 0;
        __syncthreads();
        s[t] += x;
        __syncthreads();
    }
    if (t < NBUK) bstart[t] = s[t] - v;
    if (t == 0) {
        bstart[NBUK] = NEDGES;
        row_start[NNODES] = NEDGES;
    }
}

// ---------------- pass 4: deterministic scatter into bucket order (LDS cursors) ----------------
__global__ __launch_bounds__(1024) void chunk_scatter_kernel(const int* __restrict__ src,
                                                             const int* __restrict__ dst,
                                                             const int* __restrict__ hist,
                                                             const int* __restrict__ bstart,
                                                             int* __restrict__ ebuk) {
    __shared__ int cur[NBUK];
    int c = blockIdx.x, t = threadIdx.x;
    for (int i = t; i < NBUK; i += 1024)
        cur[i] = bstart[i] + hist[c * NBUK + i];
    __syncthreads();
    int e0 = c * EPC, e1 = e0 + EPC;
    for (int e = e0 + t; e < e1; e += 1024) {
        int d = dst[e];
        int pos = atomicAdd(&cur[d >> 7], 1);
        ebuk[pos] = src[e] | ((d & 127) << 20);   // src < 2^17 fits in 20 bits
    }
}

// ---------------- per-bucket: node counts, row_start, dinv, csr fill ----------------
__global__ __launch_bounds__(256) void build_kernel(const int* __restrict__ ebuk,
                                                    const int* __restrict__ bstart,
                                                    int* __restrict__ row_start,
                                                    float* __restrict__ dinv,
                                                    int* __restrict__ csr) {
    __shared__ int cnt[128];
    __shared__ int scn[128];
    __shared__ int cur[128];
    int b = blockIdx.x;
    int t = threadIdx.x;
    int s0 = bstart[b], s1 = bstart[b + 1];
    if (t < 128) cnt[t] = 0;
    __syncthreads();
    for (int i = s0 + t; i < s1; i += 256)
        atomicAdd(&cnt[(ebuk[i] >> 20) & 127], 1);
    __syncthreads();
    if (t < 128) scn[t] = cnt[t];
    __syncthreads();
#pragma unroll
    for (int off = 1; off < 128; off <<= 1) {   // parallel inclusive scan (Hillis-Steele)
        int x = (t < 128 && t >= off) ? scn[t - off] : 0;
        __syncthreads();
        if (t < 128) scn[t] += x;
        __syncthreads();
    }
    int node = b * 128 + t;
    if (t < 128) {
        int rs = s0 + scn[t] - cnt[t];          // exclusive
        cur[t] = rs;
        if (node < NNODES) {
            row_start[node] = rs;
            dinv[node] = rsqrtf((float)cnt[t] + 1.0f);
        }
    }
    __syncthreads();
    for (int i = s0 + t; i < s1; i += 256) {
        int v = ebuk[i];
        int pos = atomicAdd(&cur[(v >> 20) & 127], 1);
        csr[pos] = v & 0xFFFFF;
    }
}

// ---------------- register-tiled GEMM (fp32 A): stage(fp8) = rowscale * (A @ W) ----------------
template <int KIN, int KOUT, int TR>
__global__ __launch_bounds__(256) void gemm_stage_kernel(const float* __restrict__ A,
                                                         const float* __restrict__ W,
                                                         const float* __restrict__ rowscale,
                                                         unsigned char* __restrict__ stage,
                                                         int nrows) {
    constexpr int COLG = KOUT / 4;
    constexpr int ROWG = 256 / COLG;
    constexpr int R    = TR / ROWG;
    constexpr int LDK  = KIN + 4;
    __shared__ float As[TR][LDK];
    int block_row = blockIdx.x * TR;
    int tid = threadIdx.x;

    constexpr int C4 = KIN / 4;
    for (int idx = tid; idx < TR * C4; idx += 256) {
        int r = idx / C4, c = idx % C4;
        float4 v = make_float4(0.f, 0.f, 0.f, 0.f);
        if (block_row + r < nrows)
            v = *(const float4*)(A + (size_t)(block_row + r) * KIN + c * 4);
        *(float4*)(&As[r][c * 4]) = v;
    }
    __syncthreads();

    int cg = tid % COLG, rg = tid / COLG;
    int j  = cg * 4;
    int r0 = rg * R;
    float4 acc[R];
#pragma unroll
    for (int r = 0; r < R; r++) acc[r] = make_float4(0.f, 0.f, 0.f, 0.f);

#pragma unroll 4
    for (int k = 0; k < KIN; k++) {
        float4 w = *(const float4*)(W + (size_t)k * KOUT + j);
#pragma unroll
        for (int r = 0; r < R; r++) {
            float a = As[r0 + r][k];
            acc[r].x += a * w.x; acc[r].y += a * w.y;
            acc[r].z += a * w.z; acc[r].w += a * w.w;
        }
    }
#pragma unroll
    for (int r = 0; r < R; r++) {
        int row = block_row + r0 + r;
        if (row < nrows) {
            float d = rowscale[row];
            int pk = __builtin_amdgcn_cvt_pk_fp8_f32(acc[r].x * d, acc[r].y * d, 0, false);
            pk = __builtin_amdgcn_cvt_pk_fp8_f32(acc[r].z * d, acc[r].w * d, pk, true);
            *(unsigned*)(stage + (size_t)row * KOUT + j) = (unsigned)pk;
        }
    }
}

// ---------------- register-tiled GEMM (bf16 A): stage(fp8) = rowscale * (A @ W) ----------------
template <int KIN, int KOUT, int TR>
__global__ __launch_bounds__(256) void gemm_stage_bf16_kernel(const unsigned short* __restrict__ A,
                                                              const float* __restrict__ W,
                                                              const float* __restrict__ rowscale,
                                                              unsigned char* __restrict__ stage,
                                                              int nrows) {
    constexpr int COLG = KOUT / 4;
    constexpr int ROWG = 256 / COLG;
    constexpr int R    = TR / ROWG;
    constexpr int LDK  = KIN + 4;
    __shared__ float As[TR][LDK];
    int block_row = blockIdx.x * TR;
    int tid = threadIdx.x;

    constexpr int C8 = KIN / 8;
    for (int idx = tid; idx < TR * C8; idx += 256) {
        int r = idx / C8, c = idx % C8;
        float f[8];
        uint4 v = make_uint4(0, 0, 0, 0);
        if (block_row + r < nrows)
            v = *(const uint4*)(A + (size_t)(block_row + r) * KIN + c * 8);
        unpack8_bf16(v, f);
#pragma unroll
        for (int i = 0; i < 8; i++) As[r][c * 8 + i] = f[i];
    }
    __syncthreads();

    int cg = tid % COLG, rg = tid / COLG;
    int j  = cg * 4;
    int r0 = rg * R;
    float4 acc[R];
#pragma unroll
    for (int r = 0; r < R; r++) acc[r] = make_float4(0.f, 0.f, 0.f, 0.f);

#pragma unroll 4
    for (int k = 0; k < KIN; k++) {
        float4 w = *(const float4*)(W + (size_t)k * KOUT + j);
#pragma unroll
        for (int r = 0; r < R; r++) {
            float a = As[r0 + r][k];
            acc[r].x += a * w.x; acc[r].y += a * w.y;
            acc[r].z += a * w.z; acc[r].w += a * w.w;
        }
    }
#pragma unroll
    for (int r = 0; r < R; r++) {
        int row = block_row + r0 + r;
        if (row < nrows) {
            float d = rowscale[row];
            int pk = __builtin_amdgcn_cvt_pk_fp8_f32(acc[r].x * d, acc[r].y * d, 0, false);
            pk = __builtin_amdgcn_cvt_pk_fp8_f32(acc[r].z * d, acc[r].w * d, pk, true);
            *(unsigned*)(stage + (size_t)row * KOUT + j) = (unsigned)pk;
        }
    }
}

// ---------------- gather K=128 fp8: 4 groups x 16 lanes; 32-edge windows, 8-deep MLP ----------------
__global__ __launch_bounds__(256) void gather128_kernel(
    const unsigned char* __restrict__ hs, const int* __restrict__ row_start,
    const int* __restrict__ csr, const float* __restrict__ dinv,
    const float* __restrict__ bias, unsigned short* __restrict__ out) {
    int wave = threadIdx.x >> 6;
    int lane = threadIdx.x & 63;
    int n = blockIdx.x * 4 + wave;
    if (n >= NNODES) return;
    int g = lane >> 4;          // 0..3: edge sub-group
    int c = lane & 15;          // uint2 index within 128 B row
    unsigned boff = (unsigned)c << 3;
    int start = row_start[n], end = row_start[n + 1];
    floatx2 acc[4];
#pragma unroll
    for (int i = 0; i < 4; i++) acc[i] = (floatx2)(0.f);
    int w = (start + 3) & ~3;
    if (w > end) w = end;
    {   // prologue: edges [start, w)
        int e2 = start + g;
        if (e2 < w) {
            unsigned o = ((unsigned)csr[e2] << 7) + boff;
            acc8_fp8(*(const uint2*)(hs + o), acc);
        }
    }
    for (; w + 32 <= end; w += 32) {          // 32-edge windows: 8 row loads in flight
        int4 ca = *(const int4*)(csr + w + 4 * g);
        int4 cbv = *(const int4*)(csr + w + 16 + 4 * g);
        uint2 v0 = *(const uint2*)(hs + (((unsigned)ca.x  << 7) + boff));
        uint2 v1 = *(const uint2*)(hs + (((unsigned)ca.y  << 7) + boff));
        uint2 v2 = *(const uint2*)(hs + (((unsigned)ca.z  << 7) + boff));
        uint2 v3 = *(const uint2*)(hs + (((unsigned)ca.w  << 7) + boff));
        uint2 v4 = *(const uint2*)(hs + (((unsigned)cbv.x << 7) + boff));
        uint2 v5 = *(const uint2*)(hs + (((unsigned)cbv.y << 7) + boff));
        uint2 v6 = *(const uint2*)(hs + (((unsigned)cbv.z << 7) + boff));
        uint2 v7 = *(const uint2*)(hs + (((unsigned)cbv.w << 7) + boff));
        acc8_fp8(v0, acc); acc8_fp8(v1, acc); acc8_fp8(v2, acc); acc8_fp8(v3, acc);
        acc8_fp8(v4, acc); acc8_fp8(v5, acc); acc8_fp8(v6, acc); acc8_fp8(v7, acc);
    }
    for (; w + 16 <= end; w += 16) {          // 16-edge windows
        int4 cs = *(const int4*)(csr + w + 4 * g);
        uint2 v0 = *(const uint2*)(hs + (((unsigned)cs.x << 7) + boff));
        uint2 v1 = *(const uint2*)(hs + (((unsigned)cs.y << 7) + boff));
        uint2 v2 = *(const uint2*)(hs + (((unsigned)cs.z << 7) + boff));
        uint2 v3 = *(const uint2*)(hs + (((unsigned)cs.w << 7) + boff));
        acc8_fp8(v0, acc); acc8_fp8(v1, acc); acc8_fp8(v2, acc); acc8_fp8(v3, acc);
    }
    for (int e2 = w + g; e2 < end; e2 += 4) {  // epilogue
        unsigned o = ((unsigned)csr[e2] << 7) + boff;
        acc8_fp8(*(const uint2*)(hs + o), acc);
    }
#pragma unroll
    for (int off = 16; off <= 32; off <<= 1)
#pragma unroll
        for (int i = 0; i < 4; i++) {
            acc[i].x += __shfl_xor(acc[i].x, off);
            acc[i].y += __shfl_xor(acc[i].y, off);
        }
    if (g == 0) {
        floatx2 s[4];
#pragma unroll
        for (int i = 0; i < 4; i++) s[i] = (floatx2)(0.f);
        acc8_fp8(*(const uint2*)(hs + (((unsigned)n << 7) + boff)), s);
        float d = dinv[n];
        int j = c * 8;
        float4 b0 = *(const float4*)(bias + j);
        float4 b1 = *(const float4*)(bias + j + 4);
        float r0 = fmaxf((acc[0].x + s[0].x) * d + b0.x, 0.f);
        float r1 = fmaxf((acc[0].y + s[0].y) * d + b0.y, 0.f);
        float r2 = fmaxf((acc[1].x + s[1].x) * d + b0.z, 0.f);
        float r3 = fmaxf((acc[1].y + s[1].y) * d + b0.w, 0.f);
        float r4 = fmaxf((acc[2].x + s[2].x) * d + b1.x, 0.f);
        float r5 = fmaxf((acc[2].y + s[2].y) * d + b1.y, 0.f);
        float r6 = fmaxf((acc[3].x + s[3].x) * d + b1.z, 0.f);
        float r7 = fmaxf((acc[3].y + s[3].y) * d + b1.w, 0.f);
        uint4 p;
        p.x = (unsigned)f2bf(r0) | ((unsigned)f2bf(r1) << 16);
        p.y = (unsigned)f2bf(r2) | ((unsigned)f2bf(r3) << 16);
        p.z = (unsigned)f2bf(r4) | ((unsigned)f2bf(r5) << 16);
        p.w = (unsigned)f2bf(r6) | ((unsigned)f2bf(r7) << 16);
        *(uint4*)(out + (((size_t)n << 7) + j)) = p;
    }
}

// ---------------- gather K=64 fp8: 4 groups x 16 lanes; 32-edge windows, 8-deep MLP ----------------
__global__ __launch_bounds__(256) void gather64_kernel(
    const unsigned char* __restrict__ hs, const int* __restrict__ row_start,
    const int* __restrict__ csr, const float* __restrict__ dinv,
    const float* __restrict__ bias, float* __restrict__ out) {
    int wave = threadIdx.x >> 6;
    int lane = threadIdx.x & 63;
    int n = blockIdx.x * 4 + wave;
    if (n >= NNODES) return;
    int g = lane >> 4;          // 0..3: edge sub-group
    int c = lane & 15;          // uint index within 64 B row
    unsigned boff = (unsigned)c << 2;
    int start = row_start[n], end = row_start[n + 1];
    floatx2 acc[2];
    acc[0] = (floatx2)(0.f); acc[1] = (floatx2)(0.f);
    int w = (start + 3) & ~3;
    if (w > end) w = end;
    {
        int e2 = start + g;
        if (e2 < w) {
            unsigned o = ((unsigned)csr[e2] << 6) + boff;
            acc4_fp8(*(const unsigned*)(hs + o), acc);
        }
    }
    for (; w + 32 <= end; w += 32) {
        int4 ca = *(const int4*)(csr + w + 4 * g);
        int4 cbv = *(const int4*)(csr + w + 16 + 4 * g);
        unsigned v0 = *(const unsigned*)(hs + (((unsigned)ca.x  << 6) + boff));
        unsigned v1 = *(const unsigned*)(hs + (((unsigned)ca.y  << 6) + boff));
        unsigned v2 = *(const unsigned*)(hs + (((unsigned)ca.z  << 6) + boff));
        unsigned v3 = *(const unsigned*)(hs + (((unsigned)ca.w  << 6) + boff));
        unsigned v4 = *(const unsigned*)(hs + (((unsigned)cbv.x << 6) + boff));
        unsigned v5 = *(const unsigned*)(hs + (((unsigned)cbv.y << 6) + boff));
        unsigned v6 = *(const unsigned*)(hs + (((unsigned)cbv.z << 6) + boff));
        unsigned v7 = *(const unsigned*)(hs + (((unsigned)cbv.w << 6) + boff));
        acc4_fp8(v0, acc); acc4_fp8(v1, acc); acc4_fp8(v2, acc); acc4_fp8(v3, acc);
        acc4_fp8(v4, acc); acc4_fp8(v5, acc); acc4_fp8(v6, acc); acc4_fp8(v7, acc);
    }
    for (; w + 16 <= end; w += 16) {
        int4 cs = *(const int4*)(csr + w + 4 * g);
        unsigned v0 = *(const unsigned*)(hs + (((unsigned)cs.x << 6) + boff));
        unsigned v1 = *(const unsigned*)(hs + (((unsigned)cs.y << 6) + boff));
        unsigned v2 = *(const unsigned*)(hs + (((unsigned)cs.z << 6) + boff));
        unsigned v3 = *(const unsigned*)(hs + (((unsigned)cs.w << 6) + boff));
        acc4_fp8(v0, acc); acc4_fp8(v1, acc); acc4_fp8(v2, acc); acc4_fp8(v3, acc);
    }
    for (int e2 = w + g; e2 < end; e2 += 4) {
        unsigned o = ((unsigned)csr[e2] << 6) + boff;
        acc4_fp8(*(const unsigned*)(hs + o), acc);
    }
#pragma unroll
    for (int off = 16; off <= 32; off <<= 1)
#pragma unroll
        for (int i = 0; i < 2; i++) {
            acc[i].x += __shfl_xor(acc[i].x, off);
            acc[i].y += __shfl_xor(acc[i].y, off);
        }
    if (g == 0) {
        floatx2 s[2];
        s[0] = (floatx2)(0.f); s[1] = (floatx2)(0.f);
        acc4_fp8(*(const unsigned*)(hs + (((unsigned)n << 6) + boff)), s);
        float d = dinv[n];
        int j = c * 4;
        float4 b4 = *(const float4*)(bias + j);
        float4 r;
        r.x = (acc[0].x + s[0].x) * d + b4.x;
        r.y = (acc[0].y + s[0].y) * d + b4.y;
        r.z = (acc[1].x + s[1].x) * d + b4.z;
        r.w = (acc[1].y + s[1].y) * d + b4.w;
        *(float4*)(out + (((size_t)n << 6) + j)) = r;
    }
}

// ---------------- fused attention + pooling (grid-stride over 64-row tiles) ----------------
__global__ __launch_bounds__(256) void attnpool_kernel(const float* __restrict__ h2,
                                                       const float* __restrict__ Wf1,
                                                       const float* __restrict__ bf1,
                                                       const float* __restrict__ Wf2,
                                                       const float* __restrict__ bf2,
                                                       float* __restrict__ ge,
                                                       float* __restrict__ ata,
                                                       float* __restrict__ colsum) {
    __shared__ float h2S[64][68];
    __shared__ float a1S[64][68];
    __shared__ float attS[64][8];
    __shared__ float colS[8][64];
    int t = threadIdx.x;
    int d0 = t >> 6;            // 0..3 (covers d and d+4)
    int j  = t & 63;
    int de = t >> 3, ee = t & 7;  // for t<64 (ata)
    float accge0 = 0.f, accge1 = 0.f, accata = 0.f, acccol = 0.f;
    int ntiles = (NNODES + 63) / 64;
    for (int tile = blockIdx.x; tile < ntiles; tile += gridDim.x) {
        int base = tile * 64;
#pragma unroll
        for (int q = 0; q < 4; q++) {
            int idx = t + q * 256;
            int r = idx >> 4, cc = (idx & 15) * 4;
            int row = base + r;
            float4 v = (row < NNODES) ? *(const float4*)(h2 + (size_t)row * 64 + cc)
                                      : make_float4(0.f, 0.f, 0.f, 0.f);
            *(float4*)(&h2S[r][cc]) = v;
        }
        __syncthreads();
        {   // phase 1: a1 = tanh(h2 @ Wf1 + bf1); 4 rows x 4 cols per thread
            int cg = t & 15, rg = t >> 4;
            int jj = cg * 4, r0 = rg * 4;
            float4 b4 = *(const float4*)(bf1 + jj);
            float4 acc[4];
#pragma unroll
            for (int r = 0; r < 4; r++) acc[r] = b4;
#pragma unroll 4
            for (int k = 0; k < 64; k++) {
                float4 wv = *(const float4*)(Wf1 + (size_t)k * 64 + jj);
#pragma unroll
                for (int r = 0; r < 4; r++) {
                    float a = h2S[r0 + r][k];
                    acc[r].x += a * wv.x; acc[r].y += a * wv.y;
                    acc[r].z += a * wv.z; acc[r].w += a * wv.w;
                }
            }
#pragma unroll
            for (int r = 0; r < 4; r++) {
                a1S[r0 + r][jj]     = tanhf(acc[r].x);
                a1S[r0 + r][jj + 1] = tanhf(acc[r].y);
                a1S[r0 + r][jj + 2] = tanhf(acc[r].z);
                a1S[r0 + r][jj + 3] = tanhf(acc[r].w);
            }
        }
        __syncthreads();
        {   // phase 2: att = exp(a1 @ Wf2 + bf2), stay in LDS
            int cc = t & 7, r = t >> 3;   // r in 0..31
#pragma unroll
            for (int h = 0; h < 2; h++) {
                int rr = r + h * 32;
                float acc = bf2[cc];
                for (int k = 0; k < 64; k++)
                    acc += a1S[rr][k] * Wf2[(size_t)k * 8 + cc];
                float ev = (base + rr < NNODES) ? __expf(acc) : 0.f;
                attS[rr][cc] = ev;
                colS[cc][rr] = ev;
            }
        }
        __syncthreads();
        // pooled accumulation
#pragma unroll 8
        for (int i = 0; i < 64; i++) {
            float hv = h2S[i][j];
            accge0 += attS[i][d0] * hv;
            accge1 += attS[i][d0 + 4] * hv;
        }
        if (t < 64) {
#pragma unroll 8
            for (int i = 0; i < 64; i++) accata += attS[i][de] * attS[i][ee];
        }
        if (t < 8) {
            float s = 0.f;
#pragma unroll
            for (int r = 0; r < 64; r++) s += colS[t][r];
            acccol += s;
        }
        __syncthreads();
    }
    atomicAdd(ge + d0 * 64 + j, accge0);
    atomicAdd(ge + (d0 + 4) * 64 + j, accge1);
    if (t < 64) atomicAdd(ata + de * 8 + ee, accata);
    if (t < 8) atomicAdd(colsum + t, acccol);
}

// ---------------- tiny epilogue ----------------
__global__ void final_kernel(const float* __restrict__ geacc, const float* __restrict__ ata,
                             const float* __restrict__ colsum, const float* __restrict__ Wl,
                             const float* __restrict__ bl, float* __restrict__ out) {
    __shared__ float geF[512];
    __shared__ float inv[8];
    __shared__ float logits[10];
    int t = threadIdx.x;
    if (t < 8) inv[t] = 1.0f / colsum[t];
    __syncthreads();
    for (int idx = t; idx < 512; idx += 64) {
        int d = idx >> 6;
        float v = geacc[idx] * inv[d];
        geF[idx] = v;
        out[idx] = v;                       // graph_embedding
    }
    __syncthreads();
    if (t == 0) {
        float pen = 0.f;
        for (int d = 0; d < 8; d++) {
            float s = 0.f;
            for (int e = 0; e < 8; e++) {
                float p = ata[d * 8 + e] * inv[d] * inv[e] - (d == e ? 1.0f : 0.0f);
                s += p * p;
            }
            pen += sqrtf(s);
        }
        out[512] = pen;                     // penalty
    }
    if (t < 10) {
        float acc = bl[t];
        for (int k = 0; k < 512; k++) acc += geF[k] * Wl[(size_t)k * 10 + t];
        logits[t] = acc;
    }
    __syncthreads();
    if (t == 0) {
        float m = -INFINITY;
        for (int l = 0; l < 10; l++) m = fmaxf(m, logits[l]);
        float s = 0.f;
        for (int l = 0; l < 10; l++) s += expf(logits[l] - m);
        float ls = logf(s);
        for (int l = 0; l < 10; l++) out[513 + l] = logits[l] - m - ls;  // log_softmax
    }
}

extern "C" void kernel_launch(void* const* d_in, const int* in_sizes, int n_in,
                              void* d_out, int out_size, void* d_ws, size_t ws_size,
                              hipStream_t stream) {
    const int* esrc = (const int*)d_in[0];
    const int* edst = esrc + NEDGES;
    const float* X   = (const float*)d_in[1];
    const float* W1  = (const float*)d_in[2];
    const float* b1  = (const float*)d_in[3];
    const float* W2  = (const float*)d_in[4];
    const float* b2  = (const float*)d_in[5];
    const float* Wf1 = (const float*)d_in[6];
    const float* bf1 = (const float*)d_in[7];
    const float* Wf2 = (const float*)d_in[8];
    const float* bf2 = (const float*)d_in[9];
    const float* Wl  = (const float*)d_in[10];
    const float* bl  = (const float*)d_in[11];
    float* out = (float*)d_out;

    // workspace layout
    float* ws     = (float*)d_ws;
    float* dinv   = ws;                               // N (padded to 100352)
    float* smalls = ws + 100352;                      // 1024
    float* colsum = smalls + 8;                       // 8
    float* ata    = smalls + 16;                      // 64
    float* geacc  = smalls + 80;                      // 512
    float* A = ws + 101376;                           // N*128 fp32 region
    float* B = A + (size_t)NNODES * 128;              // N*128 fp32 region
    int* row_start = (int*)(B + (size_t)NNODES * 128);// N+1 (padded 100352)
    int* btot      = row_start + 100352;              // NBUK (padded 1024)
    int* bstart    = btot + 1024;                     // NBUK+1 (padded 1024)
    int* csr       = bstart + 1024;                   // E
    int* ebuk      = (int*)A;                         // E temp (consumed before gemm1 writes A)
    int* hist      = (int*)B;                         // NCHUNK*NBUK temp (consumed before gather128 writes B)
    unsigned char* stage = (unsigned char*)A;         // fp8 staging (N*128 or N*64 bytes)
    unsigned short* h1 = (unsigned short*)B;          // N*128 bf16
    float* h2  = B;                                   // N*64 fp32 (overwrites h1 after gemm2 consumed it)

    // ---- CSR build + dinv (deterministic two-pass counting sort) ----
    chunk_hist_kernel<<<NCHUNK, 1024, 0, stream>>>(edst, hist);
    col_scan_kernel<<<4, 256, 0, stream>>>(hist, btot);
    bucket_scan_kernel<<<1, 1024, 0, stream>>>(btot, bstart, row_start, smalls);
    chunk_scatter_kernel<<<NCHUNK, 1024, 0, stream>>>(esrc, edst, hist, bstart, ebuk);
    build_kernel<<<NBUK, 256, 0, stream>>>(ebuk, bstart, row_start, dinv, csr);

    // ---- GCN layer 1: stage = fp8(dinv*(X@W1)); h1(bf16) = relu(gather(stage)*dinv + b1) ----
    gemm_stage_kernel<128, 128, 64><<<(NNODES + 63) / 64, 256, 0, stream>>>(X, W1, dinv, stage, NNODES);
    gather128_kernel<<<(NNODES + 3) / 4, 256, 0, stream>>>(stage, row_start, csr, dinv, b1, h1);

    // ---- GCN layer 2: stage = fp8(dinv*(h1@W2)); h2 = gather(stage)*dinv + b2 ----
    gemm_stage_bf16_kernel<128, 64, 64><<<(NNODES + 63) / 64, 256, 0, stream>>>(h1, W2, dinv, stage, NNODES);
    gather64_kernel<<<(NNODES + 3) / 4, 256, 0, stream>>>(stage, row_start, csr, dinv, b2, h2);

    // ---- fused attention + pooling ----
    attnpool_kernel<<<512, 256, 0, stream>>>(h2, Wf1, bf1, Wf2, bf2, geacc, ata, colsum);
    final_kernel<<<1, 64, 0, stream>>>(geacc, ata, colsum, Wl, bl, out);
}

// Round 11
// 430.867 us; speedup vs baseline: 1.1921x; 1.1361x over previous
//
#include <hip/hip_runtime.h>
#include <hip/hip_bf16.h>
#include <math.h>

#define NNODES 100000
#define NEDGES 3200000
#define NBUK ((NNODES + 127) >> 7)   // 782 buckets of 128 nodes
#define NCHUNK 256
#define EPC (NEDGES / NCHUNK)        // 12500 edges per chunk

typedef float floatx2 __attribute__((ext_vector_type(2)));
typedef float f32x4 __attribute__((ext_vector_type(4)));
typedef short bf16x8 __attribute__((ext_vector_type(8)));

// ---- bf16 pack/unpack ----
__device__ __forceinline__ unsigned short f2bf(float x) {
    unsigned u = __float_as_uint(x);
    unsigned r = u + 0x7FFFu + ((u >> 16) & 1u);
    return (unsigned short)(r >> 16);
}

// ---- fp8 e4m3 packed accumulate (gfx950 HW converts) ----
__device__ __forceinline__ void acc8_fp8(uint2 v, floatx2* a) {
    a[0] += __builtin_amdgcn_cvt_pk_f32_fp8(v.x, false);
    a[1] += __builtin_amdgcn_cvt_pk_f32_fp8(v.x, true);
    a[2] += __builtin_amdgcn_cvt_pk_f32_fp8(v.y, false);
    a[3] += __builtin_amdgcn_cvt_pk_f32_fp8(v.y, true);
}
__device__ __forceinline__ void acc4_fp8(unsigned v, floatx2* a) {
    a[0] += __builtin_amdgcn_cvt_pk_f32_fp8(v, false);
    a[1] += __builtin_amdgcn_cvt_pk_f32_fp8(v, true);
}

// ---------------- weight prep: Wt1[n][k]=bf16(W1[k][n]); Wt2[n][k]=bf16(W2[k][n]) ----------------
__global__ void prep_w_kernel(const float* __restrict__ W1, const float* __restrict__ W2,
                              unsigned short* __restrict__ Wt1, unsigned short* __restrict__ Wt2) {
    int i = blockIdx.x * 256 + threadIdx.x;
    if (i < 128 * 128) {
        int k = i >> 7, n = i & 127;        // coalesced read over n
        Wt1[n * 128 + k] = f2bf(W1[i]);
    } else if (i < 128 * 128 + 128 * 64) {
        int j = i - 128 * 128;
        int k = j >> 6, n = j & 63;
        Wt2[n * 128 + k] = f2bf(W2[j]);
    }
}

// ---------------- pass 1: per-chunk bucket histogram (LDS, int4 reads) ----------------
__global__ __launch_bounds__(1024) void chunk_hist_kernel(const int* __restrict__ dst,
                                                          int* __restrict__ hist) {
    __shared__ int h[NBUK];
    int c = blockIdx.x, t = threadIdx.x;
    for (int i = t; i < NBUK; i += 1024) h[i] = 0;
    __syncthreads();
    const int4* d4 = (const int4*)(dst + c * EPC);
    for (int i = t; i < EPC / 4; i += 1024) {
        int4 d = d4[i];
        atomicAdd(&h[d.x >> 7], 1);
        atomicAdd(&h[d.y >> 7], 1);
        atomicAdd(&h[d.z >> 7], 1);
        atomicAdd(&h[d.w >> 7], 1);
    }
    __syncthreads();
    for (int i = t; i < NBUK; i += 1024)
        hist[c * NBUK + i] = h[i];
}

// ---------------- pass 2: per-bucket exclusive prefix over chunks ----------------
__global__ void col_scan_kernel(int* __restrict__ hist, int* __restrict__ btot) {
    int t = blockIdx.x * 256 + threadIdx.x;
    if (t >= NBUK) return;
    int run = 0;
    for (int c = 0; c < NCHUNK; c++) {
        int idx = c * NBUK + t;
        int v = hist[idx];
        hist[idx] = run;
        run += v;
    }
    btot[t] = run;
}

// ---------------- pass 3: scan bucket totals -> bstart; zero small accumulators ----------------
__global__ void bucket_scan_kernel(const int* __restrict__ btot, int* __restrict__ bstart,
                                   int* __restrict__ row_start, float* __restrict__ smalls) {
    __shared__ int s[1024];
    int t = threadIdx.x;
    if (t < 592) smalls[t] = 0.0f;   // colsum(8) ata(64) ge(512)
    int v = (t < NBUK) ? btot[t] : 0;
    s[t] = v;
    __syncthreads();
    for (int off = 1; off < 1024; off <<= 1) {
        int x = (t >= off) ? s[t - off] : 0;
        __syncthreads();
        s[t] += x;
        __syncthreads();
    }
    if (t < NBUK) bstart[t] = s[t] - v;
    if (t == 0) {
        bstart[NBUK] = NEDGES;
        row_start[NNODES] = NEDGES;
    }
}

// ---------------- pass 4: deterministic scatter into bucket order (LDS cursors, int4 reads) ----
__global__ __launch_bounds__(1024) void chunk_scatter_kernel(const int* __restrict__ src,
                                                             const int* __restrict__ dst,
                                                             const int* __restrict__ hist,
                                                             const int* __restrict__ bstart,
                                                             int* __restrict__ ebuk) {
    __shared__ int cur[NBUK];
    int c = blockIdx.x, t = threadIdx.x;
    for (int i = t; i < NBUK; i += 1024)
        cur[i] = bstart[i] + hist[c * NBUK + i];
    __syncthreads();
    const int4* s4 = (const int4*)(src + c * EPC);
    const int4* d4 = (const int4*)(dst + c * EPC);
    for (int i = t; i < EPC / 4; i += 1024) {
        int4 s = s4[i];
        int4 d = d4[i];
        int p0 = atomicAdd(&cur[d.x >> 7], 1);
        ebuk[p0] = s.x | ((d.x & 127) << 20);
        int p1 = atomicAdd(&cur[d.y >> 7], 1);
        ebuk[p1] = s.y | ((d.y & 127) << 20);
        int p2 = atomicAdd(&cur[d.z >> 7], 1);
        ebuk[p2] = s.z | ((d.z & 127) << 20);
        int p3 = atomicAdd(&cur[d.w >> 7], 1);
        ebuk[p3] = s.w | ((d.w & 127) << 20);
    }
}

// ---------------- per-bucket: node counts, row_start, dinv, csr fill ----------------
__global__ __launch_bounds__(256) void build_kernel(const int* __restrict__ ebuk,
                                                    const int* __restrict__ bstart,
                                                    int* __restrict__ row_start,
                                                    float* __restrict__ dinv,
                                                    int* __restrict__ csr) {
    __shared__ int cnt[128];
    __shared__ int scn[128];
    __shared__ int cur[128];
    int b = blockIdx.x;
    int t = threadIdx.x;
    int s0 = bstart[b], s1 = bstart[b + 1];
    if (t < 128) cnt[t] = 0;
    __syncthreads();
    for (int i = s0 + t; i < s1; i += 256)
        atomicAdd(&cnt[(ebuk[i] >> 20) & 127], 1);
    __syncthreads();
    if (t < 128) scn[t] = cnt[t];
    __syncthreads();
#pragma unroll
    for (int off = 1; off < 128; off <<= 1) {
        int x = (t < 128 && t >= off) ? scn[t - off] : 0;
        __syncthreads();
        if (t < 128) scn[t] += x;
        __syncthreads();
    }
    int node = b * 128 + t;
    if (t < 128) {
        int rs = s0 + scn[t] - cnt[t];
        cur[t] = rs;
        if (node < NNODES) {
            row_start[node] = rs;
            dinv[node] = rsqrtf((float)cnt[t] + 1.0f);
        }
    }
    __syncthreads();
    for (int i = s0 + t; i < s1; i += 256) {
        int v = ebuk[i];
        int pos = atomicAdd(&cur[(v >> 20) & 127], 1);
        csr[pos] = v & 0xFFFFF;
    }
}

// ---------------- MFMA GEMM: stage(fp8) = rowscale * (A @ W) ----------------
// A: fp32 (ABF16=false) or bf16 (true), [N,KIN]; Wt: bf16 transposed [KOUT][KIN].
// 256 threads = 4 waves; 64-row tile; wave w handles rows w*16..w*16+15, all KOUT cols.
template <int KIN, int KOUT, bool ABF16>
__global__ __launch_bounds__(256) void gemm_mfma_kernel(const void* __restrict__ Av,
                                                        const unsigned short* __restrict__ Wt,
                                                        const float* __restrict__ rowscale,
                                                        unsigned char* __restrict__ stage) {
    constexpr int LDK = KIN + 8;          // bf16 elems; 16 B pad
    constexpr int LDC = KOUT + 4;         // fp32 elems
    constexpr int SH_AB = (64 + KOUT) * LDK * 2;
    constexpr int SH_C  = 64 * LDC * 4;
    constexpr int SH = SH_AB > SH_C ? SH_AB : SH_C;
    __shared__ char shbuf[SH];
    unsigned short* As = (unsigned short*)shbuf;       // [64][LDK]
    unsigned short* Ws = As + 64 * LDK;                // [KOUT][LDK]
    float* Cs = (float*)shbuf;                         // [64][LDC] (aliases, used after)
    int t = threadIdx.x;
    int block_row = blockIdx.x * 64;

    // stage Wt -> LDS (bf16, already transposed)
    for (int idx = t; idx < KOUT * (KIN / 8); idx += 256) {
        int n = idx / (KIN / 8), c = idx % (KIN / 8);
        *(uint4*)(Ws + n * LDK + c * 8) = *(const uint4*)(Wt + n * KIN + c * 8);
    }
    // stage A -> LDS (convert to bf16 if fp32)
    if (ABF16) {
        const unsigned short* A = (const unsigned short*)Av;
        for (int idx = t; idx < 64 * (KIN / 8); idx += 256) {
            int r = idx / (KIN / 8), c = idx % (KIN / 8);
            uint4 v = make_uint4(0, 0, 0, 0);
            if (block_row + r < NNODES)
                v = *(const uint4*)(A + (size_t)(block_row + r) * KIN + c * 8);
            *(uint4*)(As + r * LDK + c * 8) = v;
        }
    } else {
        const float* A = (const float*)Av;
        for (int idx = t; idx < 64 * (KIN / 4); idx += 256) {
            int r = idx / (KIN / 4), c = idx % (KIN / 4);
            float4 v = make_float4(0.f, 0.f, 0.f, 0.f);
            if (block_row + r < NNODES)
                v = *(const float4*)(A + (size_t)(block_row + r) * KIN + c * 4);
            unsigned p0 = (unsigned)f2bf(v.x) | ((unsigned)f2bf(v.y) << 16);
            unsigned p1 = (unsigned)f2bf(v.z) | ((unsigned)f2bf(v.w) << 16);
            *(uint2*)(As + r * LDK + c * 4) = make_uint2(p0, p1);
        }
    }
    __syncthreads();

    int wv = t >> 6, lane = t & 63;
    int r0 = wv * 16;
    int m = lane & 15, q = lane >> 4;     // A[m][k=q*8+j]; B[k=q*8+j][n=m]; C: col=m,row=q*4+reg
    constexpr int NT = KOUT / 16;
    constexpr int KS = KIN / 32;
    f32x4 acc[NT];
#pragma unroll
    for (int nt = 0; nt < NT; nt++) acc[nt] = (f32x4)(0.f);
    bf16x8 afr[KS];
#pragma unroll
    for (int ks = 0; ks < KS; ks++)
        afr[ks] = *(bf16x8*)(As + (r0 + m) * LDK + ks * 32 + q * 8);
#pragma unroll
    for (int nt = 0; nt < NT; nt++) {
#pragma unroll
        for (int ks = 0; ks < KS; ks++) {
            bf16x8 b = *(bf16x8*)(Ws + (nt * 16 + m) * LDK + ks * 32 + q * 8);
            acc[nt] = __builtin_amdgcn_mfma_f32_16x16x32_bf16(afr[ks], b, acc[nt], 0, 0, 0);
        }
    }
    __syncthreads();
    // C -> LDS (C/D layout: col=lane&15, row=(lane>>4)*4+reg)
#pragma unroll
    for (int nt = 0; nt < NT; nt++)
#pragma unroll
        for (int j = 0; j < 4; j++)
            Cs[(r0 + q * 4 + j) * LDC + nt * 16 + m] = acc[nt][j];
    __syncthreads();
    // epilogue: scale by dinv, fp8 pack, coalesced store
    for (int idx = t; idx < 64 * (KOUT / 4); idx += 256) {
        int r = idx / (KOUT / 4), c4 = idx % (KOUT / 4);
        int row = block_row + r;
        if (row < NNODES) {
            float4 v = *(float4*)(Cs + r * LDC + c4 * 4);
            float d = rowscale[row];
            int pk = __builtin_amdgcn_cvt_pk_fp8_f32(v.x * d, v.y * d, 0, false);
            pk = __builtin_amdgcn_cvt_pk_fp8_f32(v.z * d, v.w * d, pk, true);
            *(unsigned*)(stage + (size_t)row * KOUT + c4 * 4) = (unsigned)pk;
        }
    }
}

// ---------------- gather K=128 fp8: 4 groups x 16 lanes; 32-edge windows, 8-deep MLP ----------------
__global__ __launch_bounds__(256) void gather128_kernel(
    const unsigned char* __restrict__ hs, const int* __restrict__ row_start,
    const int* __restrict__ csr, const float* __restrict__ dinv,
    const float* __restrict__ bias, unsigned short* __restrict__ out) {
    int wave = threadIdx.x >> 6;
    int lane = threadIdx.x & 63;
    int n = blockIdx.x * 4 + wave;
    if (n >= NNODES) return;
    int g = lane >> 4;          // 0..3: edge sub-group
    int c = lane & 15;          // uint2 index within 128 B row
    unsigned boff = (unsigned)c << 3;
    int start = row_start[n], end = row_start[n + 1];
    floatx2 acc[4];
#pragma unroll
    for (int i = 0; i < 4; i++) acc[i] = (floatx2)(0.f);
    int w = (start + 3) & ~3;
    if (w > end) w = end;
    {
        int e2 = start + g;
        if (e2 < w) {
            unsigned o = ((unsigned)csr[e2] << 7) + boff;
            acc8_fp8(*(const uint2*)(hs + o), acc);
        }
    }
    for (; w + 32 <= end; w += 32) {
        int4 ca = *(const int4*)(csr + w + 4 * g);
        int4 cbv = *(const int4*)(csr + w + 16 + 4 * g);
        uint2 v0 = *(const uint2*)(hs + (((unsigned)ca.x  << 7) + boff));
        uint2 v1 = *(const uint2*)(hs + (((unsigned)ca.y  << 7) + boff));
        uint2 v2 = *(const uint2*)(hs + (((unsigned)ca.z  << 7) + boff));
        uint2 v3 = *(const uint2*)(hs + (((unsigned)ca.w  << 7) + boff));
        uint2 v4 = *(const uint2*)(hs + (((unsigned)cbv.x << 7) + boff));
        uint2 v5 = *(const uint2*)(hs + (((unsigned)cbv.y << 7) + boff));
        uint2 v6 = *(const uint2*)(hs + (((unsigned)cbv.z << 7) + boff));
        uint2 v7 = *(const uint2*)(hs + (((unsigned)cbv.w << 7) + boff));
        acc8_fp8(v0, acc); acc8_fp8(v1, acc); acc8_fp8(v2, acc); acc8_fp8(v3, acc);
        acc8_fp8(v4, acc); acc8_fp8(v5, acc); acc8_fp8(v6, acc); acc8_fp8(v7, acc);
    }
    for (; w + 16 <= end; w += 16) {
        int4 cs = *(const int4*)(csr + w + 4 * g);
        uint2 v0 = *(const uint2*)(hs + (((unsigned)cs.x << 7) + boff));
        uint2 v1 = *(const uint2*)(hs + (((unsigned)cs.y << 7) + boff));
        uint2 v2 = *(const uint2*)(hs + (((unsigned)cs.z << 7) + boff));
        uint2 v3 = *(const uint2*)(hs + (((unsigned)cs.w << 7) + boff));
        acc8_fp8(v0, acc); acc8_fp8(v1, acc); acc8_fp8(v2, acc); acc8_fp8(v3, acc);
    }
    for (int e2 = w + g; e2 < end; e2 += 4) {
        unsigned o = ((unsigned)csr[e2] << 7) + boff;
        acc8_fp8(*(const uint2*)(hs + o), acc);
    }
#pragma unroll
    for (int off = 16; off <= 32; off <<= 1)
#pragma unroll
        for (int i = 0; i < 4; i++) {
            acc[i].x += __shfl_xor(acc[i].x, off);
            acc[i].y += __shfl_xor(acc[i].y, off);
        }
    if (g == 0) {
        floatx2 s[4];
#pragma unroll
        for (int i = 0; i < 4; i++) s[i] = (floatx2)(0.f);
        acc8_fp8(*(const uint2*)(hs + (((unsigned)n << 7) + boff)), s);
        float d = dinv[n];
        int j = c * 8;
        float4 b0 = *(const float4*)(bias + j);
        float4 b1 = *(const float4*)(bias + j + 4);
        float r0 = fmaxf((acc[0].x + s[0].x) * d + b0.x, 0.f);
        float r1 = fmaxf((acc[0].y + s[0].y) * d + b0.y, 0.f);
        float r2 = fmaxf((acc[1].x + s[1].x) * d + b0.z, 0.f);
        float r3 = fmaxf((acc[1].y + s[1].y) * d + b0.w, 0.f);
        float r4 = fmaxf((acc[2].x + s[2].x) * d + b1.x, 0.f);
        float r5 = fmaxf((acc[2].y + s[2].y) * d + b1.y, 0.f);
        float r6 = fmaxf((acc[3].x + s[3].x) * d + b1.z, 0.f);
        float r7 = fmaxf((acc[3].y + s[3].y) * d + b1.w, 0.f);
        uint4 p;
        p.x = (unsigned)f2bf(r0) | ((unsigned)f2bf(r1) << 16);
        p.y = (unsigned)f2bf(r2) | ((unsigned)f2bf(r3) << 16);
        p.z = (unsigned)f2bf(r4) | ((unsigned)f2bf(r5) << 16);
        p.w = (unsigned)f2bf(r6) | ((unsigned)f2bf(r7) << 16);
        *(uint4*)(out + (((size_t)n << 7) + j)) = p;
    }
}

// ---------------- gather K=64 fp8: 4 groups x 16 lanes; 32-edge windows, 8-deep MLP ----------------
__global__ __launch_bounds__(256) void gather64_kernel(
    const unsigned char* __restrict__ hs, const int* __restrict__ row_start,
    const int* __restrict__ csr, const float* __restrict__ dinv,
    const float* __restrict__ bias, float* __restrict__ out) {
    int wave = threadIdx.x >> 6;
    int lane = threadIdx.x & 63;
    int n = blockIdx.x * 4 + wave;
    if (n >= NNODES) return;
    int g = lane >> 4;
    int c = lane & 15;
    unsigned boff = (unsigned)c << 2;
    int start = row_start[n], end = row_start[n + 1];
    floatx2 acc[2];
    acc[0] = (floatx2)(0.f); acc[1] = (floatx2)(0.f);
    int w = (start + 3) & ~3;
    if (w > end) w = end;
    {
        int e2 = start + g;
        if (e2 < w) {
            unsigned o = ((unsigned)csr[e2] << 6) + boff;
            acc4_fp8(*(const unsigned*)(hs + o), acc);
        }
    }
    for (; w + 32 <= end; w += 32) {
        int4 ca = *(const int4*)(csr + w + 4 * g);
        int4 cbv = *(const int4*)(csr + w + 16 + 4 * g);
        unsigned v0 = *(const unsigned*)(hs + (((unsigned)ca.x  << 6) + boff));
        unsigned v1 = *(const unsigned*)(hs + (((unsigned)ca.y  << 6) + boff));
        unsigned v2 = *(const unsigned*)(hs + (((unsigned)ca.z  << 6) + boff));
        unsigned v3 = *(const unsigned*)(hs + (((unsigned)ca.w  << 6) + boff));
        unsigned v4 = *(const unsigned*)(hs + (((unsigned)cbv.x << 6) + boff));
        unsigned v5 = *(const unsigned*)(hs + (((unsigned)cbv.y << 6) + boff));
        unsigned v6 = *(const unsigned*)(hs + (((unsigned)cbv.z << 6) + boff));
        unsigned v7 = *(const unsigned*)(hs + (((unsigned)cbv.w << 6) + boff));
        acc4_fp8(v0, acc); acc4_fp8(v1, acc); acc4_fp8(v2, acc); acc4_fp8(v3, acc);
        acc4_fp8(v4, acc); acc4_fp8(v5, acc); acc4_fp8(v6, acc); acc4_fp8(v7, acc);
    }
    for (; w + 16 <= end; w += 16) {
        int4 cs = *(const int4*)(csr + w + 4 * g);
        unsigned v0 = *(const unsigned*)(hs + (((unsigned)cs.x << 6) + boff));
        unsigned v1 = *(const unsigned*)(hs + (((unsigned)cs.y << 6) + boff));
        unsigned v2 = *(const unsigned*)(hs + (((unsigned)cs.z << 6) + boff));
        unsigned v3 = *(const unsigned*)(hs + (((unsigned)cs.w << 6) + boff));
        acc4_fp8(v0, acc); acc4_fp8(v1, acc); acc4_fp8(v2, acc); acc4_fp8(v3, acc);
    }
    for (int e2 = w + g; e2 < end; e2 += 4) {
        unsigned o = ((unsigned)csr[e2] << 6) + boff;
        acc4_fp8(*(const unsigned*)(hs + o), acc);
    }
#pragma unroll
    for (int off = 16; off <= 32; off <<= 1)
#pragma unroll
        for (int i = 0; i < 2; i++) {
            acc[i].x += __shfl_xor(acc[i].x, off);
            acc[i].y += __shfl_xor(acc[i].y, off);
        }
    if (g == 0) {
        floatx2 s[2];
        s[0] = (floatx2)(0.f); s[1] = (floatx2)(0.f);
        acc4_fp8(*(const unsigned*)(hs + (((unsigned)n << 6) + boff)), s);
        float d = dinv[n];
        int j = c * 4;
        float4 b4 = *(const float4*)(bias + j);
        float4 r;
        r.x = (acc[0].x + s[0].x) * d + b4.x;
        r.y = (acc[0].y + s[0].y) * d + b4.y;
        r.z = (acc[1].x + s[1].x) * d + b4.z;
        r.w = (acc[1].y + s[1].y) * d + b4.w;
        *(float4*)(out + (((size_t)n << 6) + j)) = r;
    }
}

// ---------------- fused attention + pooling (grid-stride over 64-row tiles) ----------------
__global__ __launch_bounds__(256) void attnpool_kernel(const float* __restrict__ h2,
                                                       const float* __restrict__ Wf1,
                                                       const float* __restrict__ bf1,
                                                       const float* __restrict__ Wf2,
                                                       const float* __restrict__ bf2,
                                                       float* __restrict__ ge,
                                                       float* __restrict__ ata,
                                                       float* __restrict__ colsum) {
    __shared__ float h2S[64][68];
    __shared__ float a1S[64][68];
    __shared__ float attS[64][8];
    __shared__ float colS[8][64];
    int t = threadIdx.x;
    int d0 = t >> 6;
    int j  = t & 63;
    int de = t >> 3, ee = t & 7;
    float accge0 = 0.f, accge1 = 0.f, accata = 0.f, acccol = 0.f;
    int ntiles = (NNODES + 63) / 64;
    for (int tile = blockIdx.x; tile < ntiles; tile += gridDim.x) {
        int base = tile * 64;
#pragma unroll
        for (int q = 0; q < 4; q++) {
            int idx = t + q * 256;
            int r = idx >> 4, cc = (idx & 15) * 4;
            int row = base + r;
            float4 v = (row < NNODES) ? *(const float4*)(h2 + (size_t)row * 64 + cc)
                                      : make_float4(0.f, 0.f, 0.f, 0.f);
            *(float4*)(&h2S[r][cc]) = v;
        }
        __syncthreads();
        {
            int cg = t & 15, rg = t >> 4;
            int jj = cg * 4, r0 = rg * 4;
            float4 b4 = *(const float4*)(bf1 + jj);
            float4 acc[4];
#pragma unroll
            for (int r = 0; r < 4; r++) acc[r] = b4;
#pragma unroll 4
            for (int k = 0; k < 64; k++) {
                float4 wv = *(const float4*)(Wf1 + (size_t)k * 64 + jj);
#pragma unroll
                for (int r = 0; r < 4; r++) {
                    float a = h2S[r0 + r][k];
                    acc[r].x += a * wv.x; acc[r].y += a * wv.y;
                    acc[r].z += a * wv.z; acc[r].w += a * wv.w;
                }
            }
#pragma unroll
            for (int r = 0; r < 4; r++) {
                a1S[r0 + r][jj]     = tanhf(acc[r].x);
                a1S[r0 + r][jj + 1] = tanhf(acc[r].y);
                a1S[r0 + r][jj + 2] = tanhf(acc[r].z);
                a1S[r0 + r][jj + 3] = tanhf(acc[r].w);
            }
        }
        __syncthreads();
        {
            int cc = t & 7, r = t >> 3;
#pragma unroll
            for (int h = 0; h < 2; h++) {
                int rr = r + h * 32;
                float acc = bf2[cc];
                for (int k = 0; k < 64; k++)
                    acc += a1S[rr][k] * Wf2[(size_t)k * 8 + cc];
                float ev = (base + rr < NNODES) ? __expf(acc) : 0.f;
                attS[rr][cc] = ev;
                colS[cc][rr] = ev;
            }
        }
        __syncthreads();
#pragma unroll 8
        for (int i = 0; i < 64; i++) {
            float hv = h2S[i][j];
            accge0 += attS[i][d0] * hv;
            accge1 += attS[i][d0 + 4] * hv;
        }
        if (t < 64) {
#pragma unroll 8
            for (int i = 0; i < 64; i++) accata += attS[i][de] * attS[i][ee];
        }
        if (t < 8) {
            float s = 0.f;
#pragma unroll
            for (int r = 0; r < 64; r++) s += colS[t][r];
            acccol += s;
        }
        __syncthreads();
    }
    atomicAdd(ge + d0 * 64 + j, accge0);
    atomicAdd(ge + (d0 + 4) * 64 + j, accge1);
    if (t < 64) atomicAdd(ata + de * 8 + ee, accata);
    if (t < 8) atomicAdd(colsum + t, acccol);
}

// ---------------- tiny epilogue ----------------
__global__ void final_kernel(const float* __restrict__ geacc, const float* __restrict__ ata,
                             const float* __restrict__ colsum, const float* __restrict__ Wl,
                             const float* __restrict__ bl, float* __restrict__ out) {
    __shared__ float geF[512];
    __shared__ float inv[8];
    __shared__ float logits[10];
    int t = threadIdx.x;
    if (t < 8) inv[t] = 1.0f / colsum[t];
    __syncthreads();
    for (int idx = t; idx < 512; idx += 64) {
        int d = idx >> 6;
        float v = geacc[idx] * inv[d];
        geF[idx] = v;
        out[idx] = v;                       // graph_embedding
    }
    __syncthreads();
    if (t == 0) {
        float pen = 0.f;
        for (int d = 0; d < 8; d++) {
            float s = 0.f;
            for (int e = 0; e < 8; e++) {
                float p = ata[d * 8 + e] * inv[d] * inv[e] - (d == e ? 1.0f : 0.0f);
                s += p * p;
            }
            pen += sqrtf(s);
        }
        out[512] = pen;                     // penalty
    }
    if (t < 10) {
        float acc = bl[t];
        for (int k = 0; k < 512; k++) acc += geF[k] * Wl[(size_t)k * 10 + t];
        logits[t] = acc;
    }
    __syncthreads();
    if (t == 0) {
        float m = -INFINITY;
        for (int l = 0; l < 10; l++) m = fmaxf(m, logits[l]);
        float s = 0.f;
        for (int l = 0; l < 10; l++) s += expf(logits[l] - m);
        float ls = logf(s);
        for (int l = 0; l < 10; l++) out[513 + l] = logits[l] - m - ls;  // log_softmax
    }
}

extern "C" void kernel_launch(void* const* d_in, const int* in_sizes, int n_in,
                              void* d_out, int out_size, void* d_ws, size_t ws_size,
                              hipStream_t stream) {
    const int* esrc = (const int*)d_in[0];
    const int* edst = esrc + NEDGES;
    const float* X   = (const float*)d_in[1];
    const float* W1  = (const float*)d_in[2];
    const float* b1  = (const float*)d_in[3];
    const float* W2  = (const float*)d_in[4];
    const float* b2  = (const float*)d_in[5];
    const float* Wf1 = (const float*)d_in[6];
    const float* bf1 = (const float*)d_in[7];
    const float* Wf2 = (const float*)d_in[8];
    const float* bf2 = (const float*)d_in[9];
    const float* Wl  = (const float*)d_in[10];
    const float* bl  = (const float*)d_in[11];
    float* out = (float*)d_out;

    // workspace layout
    float* ws     = (float*)d_ws;
    float* dinv   = ws;                               // N (padded to 100352)
    float* smalls = ws + 100352;                      // 1024
    float* colsum = smalls + 8;                       // 8
    float* ata    = smalls + 16;                      // 64
    float* geacc  = smalls + 80;                      // 512
    float* A = ws + 101376;                           // N*128 fp32 region
    float* B = A + (size_t)NNODES * 128;              // N*128 fp32 region
    int* row_start = (int*)(B + (size_t)NNODES * 128);// N+1 (padded 100352)
    int* btot      = row_start + 100352;              // NBUK (padded 1024)
    int* bstart    = btot + 1024;                     // NBUK+1 (padded 1024)
    int* csr       = bstart + 1024;                   // E
    unsigned short* Wt1 = (unsigned short*)(csr + NEDGES);  // 128*128 bf16
    unsigned short* Wt2 = Wt1 + 128 * 128;                  // 64*128 bf16
    int* ebuk      = (int*)A;                         // E temp (consumed before gemm1 writes A)
    int* hist      = (int*)B;                         // NCHUNK*NBUK temp (consumed before gather128 writes B)
    unsigned char* stage = (unsigned char*)A;         // fp8 staging (N*128 or N*64 bytes)
    unsigned short* h1 = (unsigned short*)B;          // N*128 bf16
    float* h2  = B;                                   // N*64 fp32 (overwrites h1 after gemm2 consumed it)

    // ---- weight prep (bf16, transposed) ----
    prep_w_kernel<<<96, 256, 0, stream>>>(W1, W2, Wt1, Wt2);

    // ---- CSR build + dinv (deterministic two-pass counting sort) ----
    chunk_hist_kernel<<<NCHUNK, 1024, 0, stream>>>(edst, hist);
    col_scan_kernel<<<4, 256, 0, stream>>>(hist, btot);
    bucket_scan_kernel<<<1, 1024, 0, stream>>>(btot, bstart, row_start, smalls);
    chunk_scatter_kernel<<<NCHUNK, 1024, 0, stream>>>(esrc, edst, hist, bstart, ebuk);
    build_kernel<<<NBUK, 256, 0, stream>>>(ebuk, bstart, row_start, dinv, csr);

    // ---- GCN layer 1: stage = fp8(dinv*(X@W1)) [MFMA]; h1(bf16) = relu(gather*dinv + b1) ----
    gemm_mfma_kernel<128, 128, false><<<(NNODES + 63) / 64, 256, 0, stream>>>(X, Wt1, dinv, stage);
    gather128_kernel<<<(NNODES + 3) / 4, 256, 0, stream>>>(stage, row_start, csr, dinv, b1, h1);

    // ---- GCN layer 2: stage = fp8(dinv*(h1@W2)) [MFMA]; h2 = gather*dinv + b2 ----
    gemm_mfma_kernel<128, 64, true><<<(NNODES + 63) / 64, 256, 0, stream>>>(h1, Wt2, dinv, stage);
    gather64_kernel<<<(NNODES + 3) / 4, 256, 0, stream>>>(stage, row_start, csr, dinv, b2, h2);

    // ---- fused attention + pooling ----
    attnpool_kernel<<<512, 256, 0, stream>>>(h2, Wf1, bf1, Wf2, bf2, geacc, ata, colsum);
    final_kernel<<<1, 64, 0, stream>>>(geacc, ata, colsum, Wl, bl, out);
}